// Round 6
// baseline (541.475 us; speedup 1.0000x reference)
//
#include <hip/hip_runtime.h>
#include <hip/hip_bf16.h>

#define BB 64
#define NN 2048
#define QQ 1024
#define SS 512
#define NCH 4   // n-chunks for shells
#define QK 4    // q-split for coef partials
#define QCH (QQ / QK)

__device__ const int PIDX[36] = {
    0, 2, 5, 8, 12, 17, 22, 27, 32, 38, 45, 52, 59, 66, 73, 80,
    88, 97, 106, 115, 124, 133, 142, 151, 160,
    170, 181, 192, 203, 214, 225, 236, 247, 258, 269, 280};

// ---------------- prep: transposes, pullback gather, coalesced rowsum, stats zero ----------------
__global__ __launch_bounds__(256) void k_prep(const float* __restrict__ De0,
                                              const float* __restrict__ De1,
                                              const float* __restrict__ De2,
                                              float* __restrict__ Dg0t, float* __restrict__ rs0,
                                              float* __restrict__ Det1, float* __restrict__ Det2,
                                              float* __restrict__ stats) {
    __shared__ float tile[32][33];
    int blk = blockIdx.x, tid = threadIdx.x;
    int r = tid >> 5, c = tid & 31;
    if (blk < 192) {  // D_eval1 [1024,165] -> Det1 [165][1024]
        int tq = blk & 31, tt = blk >> 5;
        int q0 = tq * 32, t0 = tt * 32;
        for (int rr = r; rr < 32; rr += 8) {
            int t = t0 + c;
            tile[rr][c] = (t < 165) ? De1[(q0 + rr) * 165 + t] : 0.f;
        }
        __syncthreads();
        for (int rr = r; rr < 32; rr += 8) {
            int t = t0 + rr;
            if (t < 165) Det1[t * QQ + q0 + c] = tile[c][rr];
        }
    } else if (blk < 288) {  // D_eval2 [1024,84] -> Det2 [84][1024]
        int i = blk - 192;
        int tq = i & 31, tt = i >> 5;
        int q0 = tq * 32, t0 = tt * 32;
        for (int rr = r; rr < 32; rr += 8) {
            int t = t0 + c;
            tile[rr][c] = (t < 84) ? De2[(q0 + rr) * 84 + t] : 0.f;
        }
        __syncthreads();
        for (int rr = r; rr < 32; rr += 8) {
            int t = t0 + rr;
            if (t < 84) Det2[t * QQ + q0 + c] = tile[c][rr];
        }
    } else if (blk < 352) {  // gather D_eval0[:, PIDX] -> Dg0t [36][1024]
        int i = blk - 288;
        int tq = i & 31, tj = i >> 5;
        int q0 = tq * 32, j0 = tj * 32;
        for (int rr = r; rr < 32; rr += 8) {
            int j = j0 + c;
            tile[rr][c] = (j < 36) ? De0[(q0 + rr) * 286 + PIDX[j]] : 0.f;
        }
        __syncthreads();
        for (int rr = r; rr < 32; rr += 8) {
            int j = j0 + rr;
            if (j < 36) Dg0t[j * QQ + q0 + c] = tile[c][rr];
        }
    } else if (blk < 356) {  // rowsum of D_eval0: wave per q, coalesced
        int w = tid >> 6, lane = tid & 63;
        int qbase = (blk - 352) * 256 + w * 64;
        for (int qi = 0; qi < 64; qi++) {
            int q = qbase + qi;
            float s = 0.f;
#pragma unroll
            for (int p = 0; p < 5; p++) {
                int idx = lane + p * 64;
                if (idx < 286) s += De0[q * 286 + idx];
            }
#pragma unroll
            for (int o = 32; o > 0; o >>= 1) s += __shfl_xor(s, o, 64);
            if (lane == 0) rs0[q] = s;
        }
    } else {
        if (tid < 224) stats[tid] = 0.f;
    }
}

// ---------------- shells: partial sums over n-chunk; pbuf[zc][shell][b][s] ----------------
__global__ __launch_bounds__(256) void k_shells(const float* __restrict__ x,
                                                const float* __restrict__ dirs,
                                                float* __restrict__ pbuf) {
    __shared__ float4 lx[NN / NCH];
    int b = blockIdx.x, shell = blockIdx.y, zc = blockIdx.z;
    const float KL = 18.033688011112042f;  // log2(e)/SIGMA2, SIGMA2=0.08
    const float* xb = x + ((size_t)b * NN + zc * (NN / NCH)) * 3;
    for (int n = threadIdx.x; n < NN / NCH; n += 256) {
        float X = xb[n * 3 + 0];
        float Y = xb[n * 3 + 1];
        float Z = xb[n * 3 + 2];
        lx[n] = make_float4(X, Y, Z, -KL * (X * X + Y * Y + Z * Z));
    }
    __syncthreads();
    float r = (shell == 0) ? 0.4f : ((shell == 1) ? 0.8f : 1.2f);
    int s0 = threadIdx.x, s1 = threadIdx.x + 256;
    float cx0 = r * dirs[(shell * SS + s0) * 3 + 0];
    float cy0 = r * dirs[(shell * SS + s0) * 3 + 1];
    float cz0 = r * dirs[(shell * SS + s0) * 3 + 2];
    float cx1 = r * dirs[(shell * SS + s1) * 3 + 0];
    float cy1 = r * dirs[(shell * SS + s1) * 3 + 1];
    float cz1 = r * dirs[(shell * SS + s1) * 3 + 2];
    float base0 = -KL * (cx0 * cx0 + cy0 * cy0 + cz0 * cz0);
    float base1 = -KL * (cx1 * cx1 + cy1 * cy1 + cz1 * cz1);
    float cxs0 = 2.f * KL * cx0, cys0 = 2.f * KL * cy0, czs0 = 2.f * KL * cz0;
    float cxs1 = 2.f * KL * cx1, cys1 = 2.f * KL * cy1, czs1 = 2.f * KL * cz1;
    float a0 = 0.f, a1 = 0.f;
#pragma unroll 8
    for (int n = 0; n < NN / NCH; n++) {
        float4 p = lx[n];
        a0 += __builtin_amdgcn_exp2f(fmaf(cxs0, p.x, fmaf(cys0, p.y, fmaf(czs0, p.z, p.w + base0))));
        a1 += __builtin_amdgcn_exp2f(fmaf(cxs1, p.x, fmaf(cys1, p.y, fmaf(czs1, p.z, p.w + base1))));
    }
    float* o = pbuf + ((size_t)(zc * 3 + shell) * BB + b) * SS;
    o[s0] = a0;
    o[s1] = a1;
}

// ---------------- sh: per-b chunk reduce + SH projection + W0 mix -> lm_ws[b][36][16] ----------------
__global__ __launch_bounds__(512) void k_sh(const float* __restrict__ pbuf,
                                            const float* __restrict__ A_sh,
                                            const float* __restrict__ W0,
                                            float* __restrict__ lm_ws) {
    __shared__ float lf[3][SS];
    __shared__ float lsh[36][3];
    int b = blockIdx.x, tid = threadIdx.x;
    for (int i = tid; i < 3 * SS; i += 512) {
        int c = i / SS, s = i % SS;
        float v = 0.f;
#pragma unroll
        for (int zc = 0; zc < NCH; zc++) v += pbuf[((size_t)(zc * 3 + c) * BB + b) * SS + s];
        lf[c][s] = v * (1.0f / NN);
    }
    __syncthreads();
    int w = tid >> 6, lane = tid & 63;
    for (int p = w; p < 108; p += 8) {
        int j = p / 3, c = p % 3;
        const float* As = A_sh + j * SS;
        float a = 0.f;
#pragma unroll
        for (int k = 0; k < 8; k++) a = fmaf(lf[c][lane + 64 * k], As[lane + 64 * k], a);
#pragma unroll
        for (int o = 32; o > 0; o >>= 1) a += __shfl_xor(a, o, 64);
        if (lane == 0) lsh[j][c] = a;
    }
    __syncthreads();
    for (int i = tid; i < 576; i += 512) {
        int j = i >> 4, u = i & 15;
        float m = 0.f;
#pragma unroll
        for (int c = 0; c < 3; c++) m = fmaf(lsh[j][c], W0[c * 16 + u], m);
        lm_ws[b * 576 + i] = m;
    }
}

// ---------------- eval0q: sparse Wigner eval + bias*rowsum + fused stats ----------------
__global__ __launch_bounds__(256) void k_eval0q(const float* __restrict__ lm_ws,
                                                const float* __restrict__ b0,
                                                const float* __restrict__ Dg0t,
                                                const float* __restrict__ rs0,
                                                float* __restrict__ yq, float* __restrict__ stats) {
    __shared__ float llm[576];
    __shared__ float lred[4][32];
    int qc = blockIdx.x, b = blockIdx.y, tid = threadIdx.x;
    for (int i = tid; i < 576; i += 256) llm[i] = lm_ws[b * 576 + i];
    __syncthreads();
    int q = qc * 256 + tid;
    float acc[16];
#pragma unroll
    for (int u = 0; u < 16; u++) acc[u] = 0.f;
#pragma unroll 4
    for (int j = 0; j < 36; j++) {
        float d = Dg0t[j * QQ + q];
#pragma unroll
        for (int u = 0; u < 16; u++) acc[u] = fmaf(d, llm[j * 16 + u], acc[u]);
    }
    float rb = rs0[q];
#pragma unroll
    for (int u = 0; u < 16; u++) acc[u] = fmaf(b0[u], rb, acc[u]);
#pragma unroll
    for (int u = 0; u < 16; u++) yq[((size_t)b * 16 + u) * QQ + q] = acc[u];
    int lane = tid & 63, w = tid >> 6;
#pragma unroll
    for (int u = 0; u < 16; u++) {
        float v = acc[u], v2 = acc[u] * acc[u];
#pragma unroll
        for (int o = 32; o > 0; o >>= 1) {
            v += __shfl_xor(v, o, 64);
            v2 += __shfl_xor(v2, o, 64);
        }
        if (lane == 0) { lred[w][u] = v; lred[w][16 + u] = v2; }
    }
    __syncthreads();
    if (tid < 32) atomicAdd(&stats[tid], lred[0][tid] + lred[1][tid] + lred[2][tid] + lred[3][tid]);
}

// ---------------- coef: BN+LReLU fused, 4t x 4u register tiles, q-split partials ----------------
// grid (tc, b, qk); block THREADS = (TILE_T/4) * (UU/4)
template <int TT, int UU, int TILE_T>
__global__ __launch_bounds__((TILE_T / 4) * (UU / 4)) void k_coefN(
    const float* __restrict__ yq, const float* __restrict__ Dc,
    const float* __restrict__ stats, const float* __restrict__ g,
    const float* __restrict__ be, float* __restrict__ part) {
    constexpr int UG = UU / 4;
    constexpr int THREADS = (TILE_T / 4) * UG;
    constexpr int QSUB = 32;
    __shared__ float lD[QSUB][TILE_T + 4];
    __shared__ float lY[QSUB][UU + 4];
    __shared__ float lsu[UU], ltu[UU];
    int tc = blockIdx.x, b = blockIdx.y, qkz = blockIdx.z, tid = threadIdx.x;
    int t0 = tc * TILE_T, q0 = qkz * QCH;
    if (tid < UU) {
        const float inv = 1.0f / (BB * QQ);
        float m = stats[tid] * inv;
        float var = stats[UU + tid] * inv - m * m;
        float s = g[tid] * rsqrtf(fmaxf(var, 0.f) + 1e-3f);
        lsu[tid] = s;
        ltu[tid] = be[tid] - m * s;
    }
    __syncthreads();
    int tg = tid / UG, ug = tid % UG;
    float acc[4][4];
#pragma unroll
    for (int i = 0; i < 4; i++)
#pragma unroll
        for (int j = 0; j < 4; j++) acc[i][j] = 0.f;
    for (int qs = 0; qs < QCH; qs += QSUB) {
        for (int i = tid; i < TILE_T * QSUB; i += THREADS) {
            int t = i / QSUB, qq = i % QSUB;
            int tglob = t0 + t;
            lD[qq][t] = (tglob < TT) ? Dc[(size_t)tglob * QQ + q0 + qs + qq] : 0.f;
        }
        for (int i = tid; i < UU * QSUB; i += THREADS) {
            int u = i / QSUB, qq = i % QSUB;
            float v = yq[((size_t)b * UU + u) * QQ + q0 + qs + qq];
            v = fmaf(v, lsu[u], ltu[u]);
            lY[qq][u] = (v > 0.f) ? v : 0.3f * v;
        }
        __syncthreads();
#pragma unroll 4
        for (int qq = 0; qq < QSUB; qq++) {
            float4 d = *(const float4*)&lD[qq][tg * 4];
            float4 y = *(const float4*)&lY[qq][ug * 4];
#pragma unroll
            for (int i = 0; i < 4; i++) {
                float dv = (&d.x)[i];
                acc[i][0] = fmaf(dv, y.x, acc[i][0]);
                acc[i][1] = fmaf(dv, y.y, acc[i][1]);
                acc[i][2] = fmaf(dv, y.z, acc[i][2]);
                acc[i][3] = fmaf(dv, y.w, acc[i][3]);
            }
        }
        __syncthreads();
    }
#pragma unroll
    for (int i = 0; i < 4; i++) {
        int t = t0 + tg * 4 + i;
        if (t < TT) {
            float4 v = make_float4(acc[i][0], acc[i][1], acc[i][2], acc[i][3]);
            *(float4*)&part[(((size_t)qkz * BB + b) * TT + t) * UU + ug * 4] = v;
        }
    }
}

// ---------------- generic eval: partial-sum staging + mix(W,b) + Wigner eval + stats ----------------
template <int TT, int CC, int UU>
__global__ __launch_bounds__(256) void k_eval(const float* __restrict__ part,
                                              const float* __restrict__ W, const float* __restrict__ bias,
                                              const float* __restrict__ Det,
                                              float* __restrict__ yq, float* __restrict__ stats) {
    __shared__ float lyt[TT * CC];
    __shared__ float lym[TT * 16];
    __shared__ float lred[4][32];
    int qc = blockIdx.x, b = blockIdx.y, uz = blockIdx.z * 16, tid = threadIdx.x;
    for (int i = tid; i < TT * CC; i += 256) {
        float v = 0.f;
#pragma unroll
        for (int k = 0; k < QK; k++) v += part[((size_t)k * BB + b) * TT * CC + i];
        lyt[i] = v;
    }
    __syncthreads();
    for (int e = tid; e < TT * 16; e += 256) {
        int t = e >> 4, ul = e & 15, u = uz + ul;
        float m = bias[u];
#pragma unroll
        for (int c = 0; c < CC; c++) m = fmaf(lyt[t * CC + c], W[c * UU + u], m);
        lym[e] = m;
    }
    __syncthreads();
    int q = qc * 256 + tid;
    float acc[16];
#pragma unroll
    for (int u = 0; u < 16; u++) acc[u] = 0.f;
#pragma unroll 4
    for (int t = 0; t < TT; t++) {
        float d = Det[t * QQ + q];
#pragma unroll
        for (int u = 0; u < 16; u++) acc[u] = fmaf(d, lym[t * 16 + u], acc[u]);
    }
#pragma unroll
    for (int u = 0; u < 16; u++) yq[((size_t)b * UU + uz + u) * QQ + q] = acc[u];
    int lane = tid & 63, w = tid >> 6;
#pragma unroll
    for (int u = 0; u < 16; u++) {
        float v = acc[u], v2 = acc[u] * acc[u];
#pragma unroll
        for (int o = 32; o > 0; o >>= 1) {
            v += __shfl_xor(v, o, 64);
            v2 += __shfl_xor(v2, o, 64);
        }
        if (lane == 0) { lred[w][u] = v; lred[w][16 + u] = v2; }
    }
    __syncthreads();
    if (tid < 32) {
        float s = lred[0][tid] + lred[1][tid] + lred[2][tid] + lred[3][tid];
        int idx = (tid < 16) ? (uz + tid) : (UU + uz + tid - 16);
        atomicAdd(&stats[idx], s);
    }
}

// ---------------- degree-wise norms from coef3 partials -> ht0 [256 feat][64 batch] ----------------
__global__ __launch_bounds__(256) void k_norms(const float* __restrict__ part, float* __restrict__ ht0) {
    int b = blockIdx.x, tid = threadIdx.x;
    int blk = tid >> 6, u = tid & 63;
    const int offs[4] = {0, 1, 10, 35};
    const int ends[4] = {1, 10, 35, 84};
    float a = 0.f;
    for (int t = offs[blk]; t < ends[blk]; t++) {
        float v = 0.f;
#pragma unroll
        for (int k = 0; k < QK; k++) v += part[(((size_t)k * BB + b) * 84 + t) * 64 + u];
        a = fmaf(v, v, a);
    }
    ht0[(blk * 64 + u) * BB + b] = sqrtf(fmaxf(a, 0.f));
}

// ---------------- fc + batch-BN + relu: wave = one j, lane = batch, shfl reductions ----------------
template <int K, int J>
__global__ __launch_bounds__(256) void k_fc(const float* __restrict__ in, const float* __restrict__ W,
                                            const float* __restrict__ bias, const float* __restrict__ g,
                                            const float* __restrict__ be, float* __restrict__ out) {
    int tid = threadIdx.x;
    int b = tid & 63;
    int w = tid >> 6;
    int j = blockIdx.x * 4 + w;
    float a0 = 0.f, a1 = 0.f, a2 = 0.f, a3 = 0.f;
#pragma unroll 4
    for (int k = 0; k < K; k += 4) {
        a0 = fmaf(in[k * BB + b], W[k * J + j], a0);
        a1 = fmaf(in[(k + 1) * BB + b], W[(k + 1) * J + j], a1);
        a2 = fmaf(in[(k + 2) * BB + b], W[(k + 2) * J + j], a2);
        a3 = fmaf(in[(k + 3) * BB + b], W[(k + 3) * J + j], a3);
    }
    float acc = ((a0 + a1) + (a2 + a3)) + bias[j];
    float s1 = acc, s2 = acc * acc;
#pragma unroll
    for (int o = 32; o > 0; o >>= 1) {
        s1 += __shfl_xor(s1, o, 64);
        s2 += __shfl_xor(s2, o, 64);
    }
    float m = s1 * (1.0f / 64.f);
    float var = s2 * (1.0f / 64.f) - m * m;
    float sc = g[j] * rsqrtf(fmaxf(var, 0.f) + 1e-3f);
    float v = (acc - m) * sc + be[j];
    out[j * BB + b] = fmaxf(v, 0.f);
}

// ---------------- output layer + softmax ----------------
__global__ __launch_bounds__(64) void k_out(const float* __restrict__ ht2, const float* __restrict__ Wout,
                                            const float* __restrict__ bout, float* __restrict__ outp) {
    __shared__ float sm[64];
    int b = blockIdx.x, o = threadIdx.x;
    float acc = 0.f;
    if (o < 40) {
        acc = bout[o];
        for (int k = 0; k < 256; k++) acc = fmaf(ht2[k * BB + b], Wout[k * 40 + o], acc);
    }
    sm[o] = (o < 40) ? acc : -3.0e38f;
    __syncthreads();
    for (int s = 32; s > 0; s >>= 1) {
        if (o < s) sm[o] = fmaxf(sm[o], sm[o + s]);
        __syncthreads();
    }
    float m = sm[0];
    __syncthreads();
    const float L2E = 1.4426950408889634f;
    float e = (o < 40) ? exp2f((acc - m) * L2E) : 0.f;
    sm[o] = e;
    __syncthreads();
    for (int s = 32; s > 0; s >>= 1) {
        if (o < s) sm[o] += sm[o + s];
        __syncthreads();
    }
    if (o < 40) outp[b * 40 + o] = e / sm[0];
}

// ---------------- workspace layout (float offsets) ----------------
#define OFF_PBUF 0          // 393216
#define OFF_DG0T 393216     // 36864
#define OFF_RS0 430080      // 1024
#define OFF_DET1 431104     // 168960
#define OFF_DET2 600064     // 86016
#define OFF_LM 686080       // 36864
#define OFF_YQ 722944       // 4194304
#define OFF_PART 4917248    // 1376256 (max over the 3 coef partials, reused)
#define OFF_HT0 6293504     // 16384
#define OFF_HT1 6309888     // 32768
#define OFF_HT2 6342656     // 16384
#define OFF_STATS 6359040   // 224

extern "C" void kernel_launch(void* const* d_in, const int* in_sizes, int n_in,
                              void* d_out, int out_size, void* d_ws, size_t ws_size,
                              hipStream_t stream) {
    const float* x = (const float*)d_in[0];
    const float* shell_dirs = (const float*)d_in[1];
    const float* A_sh = (const float*)d_in[2];
    const float* D_eval0 = (const float*)d_in[3];
    const float* D_eval1 = (const float*)d_in[4];
    const float* D_eval2 = (const float*)d_in[5];
    const float* D_coef1 = (const float*)d_in[6];
    const float* D_coef2 = (const float*)d_in[7];
    const float* D_coef_last = (const float*)d_in[8];
    const float* W0 = (const float*)d_in[9];
    const float* b0 = (const float*)d_in[10];
    const float* W1 = (const float*)d_in[11];
    const float* b1 = (const float*)d_in[12];
    const float* W2 = (const float*)d_in[13];
    const float* b2 = (const float*)d_in[14];
    const float* g0 = (const float*)d_in[15];
    const float* be0 = (const float*)d_in[16];
    const float* g1 = (const float*)d_in[17];
    const float* be1 = (const float*)d_in[18];
    const float* g2 = (const float*)d_in[19];
    const float* be2 = (const float*)d_in[20];
    const float* Wfc1 = (const float*)d_in[21];
    const float* bfc1 = (const float*)d_in[22];
    const float* gfc1 = (const float*)d_in[23];
    const float* befc1 = (const float*)d_in[24];
    const float* Wfc2 = (const float*)d_in[25];
    const float* bfc2 = (const float*)d_in[26];
    const float* gfc2 = (const float*)d_in[27];
    const float* befc2 = (const float*)d_in[28];
    const float* Wout = (const float*)d_in[29];
    const float* bout = (const float*)d_in[30];
    float* out = (float*)d_out;

    float* ws = (float*)d_ws;
    float* pbuf = ws + OFF_PBUF;
    float* Dg0t = ws + OFF_DG0T;
    float* rs0 = ws + OFF_RS0;
    float* Det1 = ws + OFF_DET1;
    float* Det2 = ws + OFF_DET2;
    float* lm_ws = ws + OFF_LM;
    float* yq = ws + OFF_YQ;
    float* part = ws + OFF_PART;
    float* ht0 = ws + OFF_HT0;
    float* ht1 = ws + OFF_HT1;
    float* ht2 = ws + OFF_HT2;
    float* stats = ws + OFF_STATS;
    float* stats0 = stats;       // 32
    float* stats1 = stats + 32;  // 64
    float* stats2 = stats + 96;  // 128

    k_prep<<<357, 256, 0, stream>>>(D_eval0, D_eval1, D_eval2, Dg0t, rs0, Det1, Det2, stats);
    k_shells<<<dim3(BB, 3, NCH), 256, 0, stream>>>(x, shell_dirs, pbuf);
    k_sh<<<BB, 512, 0, stream>>>(pbuf, A_sh, W0, lm_ws);
    k_eval0q<<<dim3(4, BB), 256, 0, stream>>>(lm_ws, b0, Dg0t, rs0, yq, stats0);
    k_coefN<165, 16, 192><<<dim3(1, BB, QK), 192, 0, stream>>>(yq, D_coef1, stats0, g0, be0, part);
    k_eval<165, 16, 32><<<dim3(4, BB, 2), 256, 0, stream>>>(part, W1, b1, Det1, yq, stats1);
    k_coefN<84, 32, 96><<<dim3(1, BB, QK), 192, 0, stream>>>(yq, D_coef2, stats1, g1, be1, part);
    k_eval<84, 32, 64><<<dim3(4, BB, 4), 256, 0, stream>>>(part, W2, b2, Det2, yq, stats2);
    k_coefN<84, 64, 48><<<dim3(2, BB, QK), 192, 0, stream>>>(yq, D_coef_last, stats2, g2, be2, part);
    k_norms<<<BB, 256, 0, stream>>>(part, ht0);
    k_fc<256, 512><<<128, 256, 0, stream>>>(ht0, Wfc1, bfc1, gfc1, befc1, ht1);
    k_fc<512, 256><<<64, 256, 0, stream>>>(ht1, Wfc2, bfc2, gfc2, befc2, ht2);
    k_out<<<BB, 64, 0, stream>>>(ht2, Wout, bout, out);
}

// Round 7
// 448.505 us; speedup vs baseline: 1.2073x; 1.2073x over previous
//
#include <hip/hip_runtime.h>
#include <hip/hip_bf16.h>

#define BB 64
#define NN 2048
#define QQ 1024
#define SS 512
#define NCH 4    // n-chunks for shells
#define QKN3 4   // k-split for coef3 (norms consumer)

__device__ const int PIDX[36] = {
    0, 2, 5, 8, 12, 17, 22, 27, 32, 38, 45, 52, 59, 66, 73, 80,
    88, 97, 106, 115, 124, 133, 142, 151, 160,
    170, 181, 192, 203, 214, 225, 236, 247, 258, 269, 280};

// ---------------- prep: transposes, pullback gather, coalesced rowsum, stats zero ----------------
__global__ __launch_bounds__(256) void k_prep(const float* __restrict__ De0,
                                              const float* __restrict__ De1,
                                              const float* __restrict__ De2,
                                              float* __restrict__ Dg0t, float* __restrict__ rs0,
                                              float* __restrict__ Det1, float* __restrict__ Det2,
                                              float* __restrict__ stats) {
    __shared__ float tile[32][33];
    int blk = blockIdx.x, tid = threadIdx.x;
    int r = tid >> 5, c = tid & 31;
    if (blk < 192) {  // D_eval1 [1024,165] -> Det1 [165][1024]
        int tq = blk & 31, tt = blk >> 5;
        int q0 = tq * 32, t0 = tt * 32;
        for (int rr = r; rr < 32; rr += 8) {
            int t = t0 + c;
            tile[rr][c] = (t < 165) ? De1[(q0 + rr) * 165 + t] : 0.f;
        }
        __syncthreads();
        for (int rr = r; rr < 32; rr += 8) {
            int t = t0 + rr;
            if (t < 165) Det1[t * QQ + q0 + c] = tile[c][rr];
        }
    } else if (blk < 288) {  // D_eval2 [1024,84] -> Det2 [84][1024]
        int i = blk - 192;
        int tq = i & 31, tt = i >> 5;
        int q0 = tq * 32, t0 = tt * 32;
        for (int rr = r; rr < 32; rr += 8) {
            int t = t0 + c;
            tile[rr][c] = (t < 84) ? De2[(q0 + rr) * 84 + t] : 0.f;
        }
        __syncthreads();
        for (int rr = r; rr < 32; rr += 8) {
            int t = t0 + rr;
            if (t < 84) Det2[t * QQ + q0 + c] = tile[c][rr];
        }
    } else if (blk < 352) {  // gather D_eval0[:, PIDX] -> Dg0t [36][1024]
        int i = blk - 288;
        int tq = i & 31, tj = i >> 5;
        int q0 = tq * 32, j0 = tj * 32;
        for (int rr = r; rr < 32; rr += 8) {
            int j = j0 + c;
            tile[rr][c] = (j < 36) ? De0[(q0 + rr) * 286 + PIDX[j]] : 0.f;
        }
        __syncthreads();
        for (int rr = r; rr < 32; rr += 8) {
            int j = j0 + rr;
            if (j < 36) Dg0t[j * QQ + q0 + c] = tile[c][rr];
        }
    } else if (blk < 356) {  // rowsum of D_eval0: wave per q, coalesced
        int w = tid >> 6, lane = tid & 63;
        int qbase = (blk - 352) * 256 + w * 64;
        for (int qi = 0; qi < 64; qi++) {
            int q = qbase + qi;
            float s = 0.f;
#pragma unroll
            for (int p = 0; p < 5; p++) {
                int idx = lane + p * 64;
                if (idx < 286) s += De0[q * 286 + idx];
            }
#pragma unroll
            for (int o = 32; o > 0; o >>= 1) s += __shfl_xor(s, o, 64);
            if (lane == 0) rs0[q] = s;
        }
    } else {
        if (tid < 224) stats[tid] = 0.f;
    }
}

// ---------------- shells: partial sums over n-chunk; pbuf[zc][shell][b][s] ----------------
__global__ __launch_bounds__(256) void k_shells(const float* __restrict__ x,
                                                const float* __restrict__ dirs,
                                                float* __restrict__ pbuf) {
    __shared__ float4 lx[NN / NCH];
    int b = blockIdx.x, shell = blockIdx.y, zc = blockIdx.z;
    const float KL = 18.033688011112042f;  // log2(e)/SIGMA2, SIGMA2=0.08
    const float* xb = x + ((size_t)b * NN + zc * (NN / NCH)) * 3;
    for (int n = threadIdx.x; n < NN / NCH; n += 256) {
        float X = xb[n * 3 + 0];
        float Y = xb[n * 3 + 1];
        float Z = xb[n * 3 + 2];
        lx[n] = make_float4(X, Y, Z, -KL * (X * X + Y * Y + Z * Z));
    }
    __syncthreads();
    float r = (shell == 0) ? 0.4f : ((shell == 1) ? 0.8f : 1.2f);
    int s0 = threadIdx.x, s1 = threadIdx.x + 256;
    float cx0 = r * dirs[(shell * SS + s0) * 3 + 0];
    float cy0 = r * dirs[(shell * SS + s0) * 3 + 1];
    float cz0 = r * dirs[(shell * SS + s0) * 3 + 2];
    float cx1 = r * dirs[(shell * SS + s1) * 3 + 0];
    float cy1 = r * dirs[(shell * SS + s1) * 3 + 1];
    float cz1 = r * dirs[(shell * SS + s1) * 3 + 2];
    float base0 = -KL * (cx0 * cx0 + cy0 * cy0 + cz0 * cz0);
    float base1 = -KL * (cx1 * cx1 + cy1 * cy1 + cz1 * cz1);
    float cxs0 = 2.f * KL * cx0, cys0 = 2.f * KL * cy0, czs0 = 2.f * KL * cz0;
    float cxs1 = 2.f * KL * cx1, cys1 = 2.f * KL * cy1, czs1 = 2.f * KL * cz1;
    float a0 = 0.f, a1 = 0.f;
#pragma unroll 8
    for (int n = 0; n < NN / NCH; n++) {
        float4 p = lx[n];
        a0 += __builtin_amdgcn_exp2f(fmaf(cxs0, p.x, fmaf(cys0, p.y, fmaf(czs0, p.z, p.w + base0))));
        a1 += __builtin_amdgcn_exp2f(fmaf(cxs1, p.x, fmaf(cys1, p.y, fmaf(czs1, p.z, p.w + base1))));
    }
    float* o = pbuf + ((size_t)(zc * 3 + shell) * BB + b) * SS;
    o[s0] = a0;
    o[s1] = a1;
}

// ---------------- sh: per-b chunk reduce + SH projection + W0 mix -> lm_ws[b][36][16] ----------------
__global__ __launch_bounds__(512) void k_sh(const float* __restrict__ pbuf,
                                            const float* __restrict__ A_sh,
                                            const float* __restrict__ W0,
                                            float* __restrict__ lm_ws) {
    __shared__ float lf[3][SS];
    __shared__ float lsh[36][3];
    int b = blockIdx.x, tid = threadIdx.x;
    for (int i = tid; i < 3 * SS; i += 512) {
        int c = i / SS, s = i % SS;
        float v = 0.f;
#pragma unroll
        for (int zc = 0; zc < NCH; zc++) v += pbuf[((size_t)(zc * 3 + c) * BB + b) * SS + s];
        lf[c][s] = v * (1.0f / NN);
    }
    __syncthreads();
    int w = tid >> 6, lane = tid & 63;
    for (int p = w; p < 108; p += 8) {
        int j = p / 3, c = p % 3;
        const float* As = A_sh + j * SS;
        float a = 0.f;
#pragma unroll
        for (int k = 0; k < 8; k++) a = fmaf(lf[c][lane + 64 * k], As[lane + 64 * k], a);
#pragma unroll
        for (int o = 32; o > 0; o >>= 1) a += __shfl_xor(a, o, 64);
        if (lane == 0) lsh[j][c] = a;
    }
    __syncthreads();
    for (int i = tid; i < 576; i += 512) {
        int j = i >> 4, u = i & 15;
        float m = 0.f;
#pragma unroll
        for (int c = 0; c < 3; c++) m = fmaf(lsh[j][c], W0[c * 16 + u], m);
        lm_ws[b * 576 + i] = m;
    }
}

// ---------------- eval0q: sparse Wigner eval + bias*rowsum + fused stats ----------------
__global__ __launch_bounds__(256) void k_eval0q(const float* __restrict__ lm_ws,
                                                const float* __restrict__ b0,
                                                const float* __restrict__ Dg0t,
                                                const float* __restrict__ rs0,
                                                float* __restrict__ yq, float* __restrict__ stats) {
    __shared__ float llm[576];
    __shared__ float lred[4][32];
    int qc = blockIdx.x, b = blockIdx.y, tid = threadIdx.x;
    for (int i = tid; i < 576; i += 256) llm[i] = lm_ws[b * 576 + i];
    __syncthreads();
    int q = qc * 256 + tid;
    float acc[16];
#pragma unroll
    for (int u = 0; u < 16; u++) acc[u] = 0.f;
#pragma unroll 4
    for (int j = 0; j < 36; j++) {
        float d = Dg0t[j * QQ + q];
#pragma unroll
        for (int u = 0; u < 16; u++) acc[u] = fmaf(d, llm[j * 16 + u], acc[u]);
    }
    float rb = rs0[q];
#pragma unroll
    for (int u = 0; u < 16; u++) acc[u] = fmaf(b0[u], rb, acc[u]);
#pragma unroll
    for (int u = 0; u < 16; u++) yq[((size_t)b * 16 + u) * QQ + q] = acc[u];
    int lane = tid & 63, w = tid >> 6;
#pragma unroll
    for (int u = 0; u < 16; u++) {
        float v = acc[u], v2 = acc[u] * acc[u];
#pragma unroll
        for (int o = 32; o > 0; o >>= 1) {
            v += __shfl_xor(v, o, 64);
            v2 += __shfl_xor(v2, o, 64);
        }
        if (lane == 0) { lred[w][u] = v; lred[w][16 + u] = v2; }
    }
    __syncthreads();
    if (tid < 32) atomicAdd(&stats[tid], lred[0][tid] + lred[1][tid] + lred[2][tid] + lred[3][tid]);
}

// ---------------- coef as tiled GEMM: out[b][t][u] partials = D(TTxK) . act(Y)^T ----------------
// grid (mt, nt, qk); 256 thr = 16x16; 64m x 64n block tile; 4x4 per thread; k staged 32/iter.
// N-dim n = b*UU + u (rows of yq). BN+LReLU applied at staging.
template <int TT, int UU, int QKN>
__global__ __launch_bounds__(256) void k_coefG(const float* __restrict__ yq,
                                               const float* __restrict__ Dc,
                                               const float* __restrict__ stats,
                                               const float* __restrict__ g,
                                               const float* __restrict__ be,
                                               float* __restrict__ part) {
    constexpr int KC = QQ / QKN;
    __shared__ float lA[32][68];  // [kk][m]
    __shared__ float lB[32][68];  // [kk][n]
    __shared__ float lsu[UU], ltu[UU];
    int mt = blockIdx.x, nt = blockIdx.y, qk = blockIdx.z, tid = threadIdx.x;
    int m0 = mt * 64, n0 = nt * 64, k0 = qk * KC;
    if (tid < UU) {
        const float inv = 1.0f / (BB * QQ);
        float mm = stats[tid] * inv;
        float var = stats[UU + tid] * inv - mm * mm;
        float s = g[tid] * rsqrtf(fmaxf(var, 0.f) + 1e-3f);
        lsu[tid] = s;
        ltu[tid] = be[tid] - mm * s;
    }
    __syncthreads();
    int tg = tid >> 4, ug = tid & 15;
    int sr = tid >> 2;           // staged row 0..63
    int sk = (tid & 3) * 8;      // k sub-offset
    const float* drow = (m0 + sr < TT) ? (Dc + (size_t)(m0 + sr) * QQ) : nullptr;
    const float* yrow = yq + (size_t)(n0 + sr) * QQ;
    float su = lsu[(n0 + sr) % UU];
    float tu = ltu[(n0 + sr) % UU];
    float acc[4][4];
#pragma unroll
    for (int i = 0; i < 4; i++)
#pragma unroll
        for (int j = 0; j < 4; j++) acc[i][j] = 0.f;
    for (int kb = 0; kb < KC; kb += 32) {
        int kg = k0 + kb + sk;
#pragma unroll
        for (int jj = 0; jj < 8; jj++) {
            lA[sk + jj][sr] = drow ? drow[kg + jj] : 0.f;
            float bv = fmaf(yrow[kg + jj], su, tu);
            lB[sk + jj][sr] = (bv > 0.f) ? bv : 0.3f * bv;
        }
        __syncthreads();
#pragma unroll 2
        for (int kk = 0; kk < 32; kk++) {
            float4 a4 = *(const float4*)&lA[kk][tg * 4];
            float4 b4 = *(const float4*)&lB[kk][ug * 4];
#pragma unroll
            for (int i = 0; i < 4; i++) {
                float av = (&a4.x)[i];
                acc[i][0] = fmaf(av, b4.x, acc[i][0]);
                acc[i][1] = fmaf(av, b4.y, acc[i][1]);
                acc[i][2] = fmaf(av, b4.z, acc[i][2]);
                acc[i][3] = fmaf(av, b4.w, acc[i][3]);
            }
        }
        __syncthreads();
    }
    int n = n0 + ug * 4;
    int b = n / UU, u0 = n % UU;  // 4 consecutive u within one b (UU multiple of 16)
#pragma unroll
    for (int i = 0; i < 4; i++) {
        int t = m0 + tg * 4 + i;
        if (t < TT)
            *(float4*)&part[(((size_t)qk * BB + b) * TT + t) * UU + u0] =
                make_float4(acc[i][0], acc[i][1], acc[i][2], acc[i][3]);
    }
}

// ---------------- generic eval: QKN partial-sum staging + mix(W,b) + Wigner eval + stats ----------------
template <int TT, int CC, int UU, int QKN>
__global__ __launch_bounds__(256) void k_eval(const float* __restrict__ part,
                                              const float* __restrict__ W, const float* __restrict__ bias,
                                              const float* __restrict__ Det,
                                              float* __restrict__ yq, float* __restrict__ stats) {
    __shared__ float lyt[TT * CC];
    __shared__ float lym[TT * 16];
    __shared__ float lred[4][32];
    int qc = blockIdx.x, b = blockIdx.y, uz = blockIdx.z * 16, tid = threadIdx.x;
    for (int i = tid; i < TT * CC; i += 256) {
        float v = 0.f;
#pragma unroll
        for (int k = 0; k < QKN; k++) v += part[((size_t)k * BB + b) * TT * CC + i];
        lyt[i] = v;
    }
    __syncthreads();
    for (int e = tid; e < TT * 16; e += 256) {
        int t = e >> 4, ul = e & 15, u = uz + ul;
        float m = bias[u];
#pragma unroll
        for (int c = 0; c < CC; c++) m = fmaf(lyt[t * CC + c], W[c * UU + u], m);
        lym[e] = m;
    }
    __syncthreads();
    int q = qc * 256 + tid;
    float acc[16];
#pragma unroll
    for (int u = 0; u < 16; u++) acc[u] = 0.f;
#pragma unroll 4
    for (int t = 0; t < TT; t++) {
        float d = Det[t * QQ + q];
#pragma unroll
        for (int u = 0; u < 16; u++) acc[u] = fmaf(d, lym[t * 16 + u], acc[u]);
    }
#pragma unroll
    for (int u = 0; u < 16; u++) yq[((size_t)b * UU + uz + u) * QQ + q] = acc[u];
    int lane = tid & 63, w = tid >> 6;
#pragma unroll
    for (int u = 0; u < 16; u++) {
        float v = acc[u], v2 = acc[u] * acc[u];
#pragma unroll
        for (int o = 32; o > 0; o >>= 1) {
            v += __shfl_xor(v, o, 64);
            v2 += __shfl_xor(v2, o, 64);
        }
        if (lane == 0) { lred[w][u] = v; lred[w][16 + u] = v2; }
    }
    __syncthreads();
    if (tid < 32) {
        float s = lred[0][tid] + lred[1][tid] + lred[2][tid] + lred[3][tid];
        int idx = (tid < 16) ? (uz + tid) : (UU + uz + tid - 16);
        atomicAdd(&stats[idx], s);
    }
}

// ---------------- degree-wise norms from coef3 partials -> ht0 [256 feat][64 batch] ----------------
__global__ __launch_bounds__(256) void k_norms(const float* __restrict__ part, float* __restrict__ ht0) {
    int b = blockIdx.x, tid = threadIdx.x;
    int blk = tid >> 6, u = tid & 63;
    const int offs[4] = {0, 1, 10, 35};
    const int ends[4] = {1, 10, 35, 84};
    float a = 0.f;
    for (int t = offs[blk]; t < ends[blk]; t++) {
        float v = 0.f;
#pragma unroll
        for (int k = 0; k < QKN3; k++) v += part[(((size_t)k * BB + b) * 84 + t) * 64 + u];
        a = fmaf(v, v, a);
    }
    ht0[(blk * 64 + u) * BB + b] = sqrtf(fmaxf(a, 0.f));
}

// ---------------- fc + batch-BN + relu: wave = one j, lane = batch, shfl reductions ----------------
template <int K, int J>
__global__ __launch_bounds__(256) void k_fc(const float* __restrict__ in, const float* __restrict__ W,
                                            const float* __restrict__ bias, const float* __restrict__ g,
                                            const float* __restrict__ be, float* __restrict__ out) {
    int tid = threadIdx.x;
    int b = tid & 63;
    int w = tid >> 6;
    int j = blockIdx.x * 4 + w;
    float a0 = 0.f, a1 = 0.f, a2 = 0.f, a3 = 0.f;
#pragma unroll 4
    for (int k = 0; k < K; k += 4) {
        a0 = fmaf(in[k * BB + b], W[k * J + j], a0);
        a1 = fmaf(in[(k + 1) * BB + b], W[(k + 1) * J + j], a1);
        a2 = fmaf(in[(k + 2) * BB + b], W[(k + 2) * J + j], a2);
        a3 = fmaf(in[(k + 3) * BB + b], W[(k + 3) * J + j], a3);
    }
    float acc = ((a0 + a1) + (a2 + a3)) + bias[j];
    float s1 = acc, s2 = acc * acc;
#pragma unroll
    for (int o = 32; o > 0; o >>= 1) {
        s1 += __shfl_xor(s1, o, 64);
        s2 += __shfl_xor(s2, o, 64);
    }
    float m = s1 * (1.0f / 64.f);
    float var = s2 * (1.0f / 64.f) - m * m;
    float sc = g[j] * rsqrtf(fmaxf(var, 0.f) + 1e-3f);
    float v = (acc - m) * sc + be[j];
    out[j * BB + b] = fmaxf(v, 0.f);
}

// ---------------- output layer + softmax ----------------
__global__ __launch_bounds__(64) void k_out(const float* __restrict__ ht2, const float* __restrict__ Wout,
                                            const float* __restrict__ bout, float* __restrict__ outp) {
    __shared__ float sm[64];
    int b = blockIdx.x, o = threadIdx.x;
    float acc = 0.f;
    if (o < 40) {
        acc = bout[o];
        for (int k = 0; k < 256; k++) acc = fmaf(ht2[k * BB + b], Wout[k * 40 + o], acc);
    }
    sm[o] = (o < 40) ? acc : -3.0e38f;
    __syncthreads();
    for (int s = 32; s > 0; s >>= 1) {
        if (o < s) sm[o] = fmaxf(sm[o], sm[o + s]);
        __syncthreads();
    }
    float m = sm[0];
    __syncthreads();
    const float L2E = 1.4426950408889634f;
    float e = (o < 40) ? exp2f((acc - m) * L2E) : 0.f;
    sm[o] = e;
    __syncthreads();
    for (int s = 32; s > 0; s >>= 1) {
        if (o < s) sm[o] += sm[o + s];
        __syncthreads();
    }
    if (o < 40) outp[b * 40 + o] = e / sm[0];
}

// ---------------- workspace layout (float offsets) ----------------
#define OFF_PBUF 0          // 393216
#define OFF_DG0T 393216     // 36864
#define OFF_RS0 430080      // 1024
#define OFF_DET1 431104     // 168960
#define OFF_DET2 600064     // 86016
#define OFF_LM 686080       // 36864
#define OFF_YQ 722944       // 4194304
#define OFF_PART 4917248    // 1376256 (max over the 3 coef partials, reused)
#define OFF_HT0 6293504     // 16384
#define OFF_HT1 6309888     // 32768
#define OFF_HT2 6342656     // 16384
#define OFF_STATS 6359040   // 224

extern "C" void kernel_launch(void* const* d_in, const int* in_sizes, int n_in,
                              void* d_out, int out_size, void* d_ws, size_t ws_size,
                              hipStream_t stream) {
    const float* x = (const float*)d_in[0];
    const float* shell_dirs = (const float*)d_in[1];
    const float* A_sh = (const float*)d_in[2];
    const float* D_eval0 = (const float*)d_in[3];
    const float* D_eval1 = (const float*)d_in[4];
    const float* D_eval2 = (const float*)d_in[5];
    const float* D_coef1 = (const float*)d_in[6];
    const float* D_coef2 = (const float*)d_in[7];
    const float* D_coef_last = (const float*)d_in[8];
    const float* W0 = (const float*)d_in[9];
    const float* b0 = (const float*)d_in[10];
    const float* W1 = (const float*)d_in[11];
    const float* b1 = (const float*)d_in[12];
    const float* W2 = (const float*)d_in[13];
    const float* b2 = (const float*)d_in[14];
    const float* g0 = (const float*)d_in[15];
    const float* be0 = (const float*)d_in[16];
    const float* g1 = (const float*)d_in[17];
    const float* be1 = (const float*)d_in[18];
    const float* g2 = (const float*)d_in[19];
    const float* be2 = (const float*)d_in[20];
    const float* Wfc1 = (const float*)d_in[21];
    const float* bfc1 = (const float*)d_in[22];
    const float* gfc1 = (const float*)d_in[23];
    const float* befc1 = (const float*)d_in[24];
    const float* Wfc2 = (const float*)d_in[25];
    const float* bfc2 = (const float*)d_in[26];
    const float* gfc2 = (const float*)d_in[27];
    const float* befc2 = (const float*)d_in[28];
    const float* Wout = (const float*)d_in[29];
    const float* bout = (const float*)d_in[30];
    float* out = (float*)d_out;

    float* ws = (float*)d_ws;
    float* pbuf = ws + OFF_PBUF;
    float* Dg0t = ws + OFF_DG0T;
    float* rs0 = ws + OFF_RS0;
    float* Det1 = ws + OFF_DET1;
    float* Det2 = ws + OFF_DET2;
    float* lm_ws = ws + OFF_LM;
    float* yq = ws + OFF_YQ;
    float* part = ws + OFF_PART;
    float* ht0 = ws + OFF_HT0;
    float* ht1 = ws + OFF_HT1;
    float* ht2 = ws + OFF_HT2;
    float* stats = ws + OFF_STATS;
    float* stats0 = stats;       // 32
    float* stats1 = stats + 32;  // 64
    float* stats2 = stats + 96;  // 128

    k_prep<<<357, 256, 0, stream>>>(D_eval0, D_eval1, D_eval2, Dg0t, rs0, Det1, Det2, stats);
    k_shells<<<dim3(BB, 3, NCH), 256, 0, stream>>>(x, shell_dirs, pbuf);
    k_sh<<<BB, 512, 0, stream>>>(pbuf, A_sh, W0, lm_ws);
    k_eval0q<<<dim3(4, BB), 256, 0, stream>>>(lm_ws, b0, Dg0t, rs0, yq, stats0);
    // coef1: M=165 (3 m-tiles), N=64*16=1024 (16 n-tiles), k-split 8 -> 384 blocks
    k_coefG<165, 16, 8><<<dim3(3, 16, 8), 256, 0, stream>>>(yq, D_coef1, stats0, g0, be0, part);
    k_eval<165, 16, 32, 8><<<dim3(4, BB, 2), 256, 0, stream>>>(part, W1, b1, Det1, yq, stats1);
    // coef2: M=84 (2), N=2048 (32), k-split 8 -> 512 blocks
    k_coefG<84, 32, 8><<<dim3(2, 32, 8), 256, 0, stream>>>(yq, D_coef2, stats1, g1, be1, part);
    k_eval<84, 32, 64, 8><<<dim3(4, BB, 4), 256, 0, stream>>>(part, W2, b2, Det2, yq, stats2);
    // coef3: M=84 (2), N=4096 (64), k-split 4 -> 512 blocks
    k_coefG<84, 64, QKN3><<<dim3(2, 64, QKN3), 256, 0, stream>>>(yq, D_coef_last, stats2, g2, be2, part);
    k_norms<<<BB, 256, 0, stream>>>(part, ht0);
    k_fc<256, 512><<<128, 256, 0, stream>>>(ht0, Wfc1, bfc1, gfc1, befc1, ht1);
    k_fc<512, 256><<<64, 256, 0, stream>>>(ht1, Wfc2, bfc2, gfc2, befc2, ht2);
    k_out<<<BB, 64, 0, stream>>>(ht2, Wout, bout, out);
}

// Round 8
// 428.572 us; speedup vs baseline: 1.2634x; 1.0465x over previous
//
#include <hip/hip_runtime.h>
#include <hip/hip_bf16.h>

#define BB 64
#define NN 2048
#define QQ 1024
#define SS 512
#define NCH 8    // n-chunks for shells
#define QKN3 4   // k-split for coef3 (norms consumer)

__device__ const int PIDX[36] = {
    0, 2, 5, 8, 12, 17, 22, 27, 32, 38, 45, 52, 59, 66, 73, 80,
    88, 97, 106, 115, 124, 133, 142, 151, 160,
    170, 181, 192, 203, 214, 225, 236, 247, 258, 269, 280};

// ---------------- prep: transposes, pullback gather, parallel rowsum, stats zero ----------------
__global__ __launch_bounds__(256) void k_prep(const float* __restrict__ De0,
                                              const float* __restrict__ De1,
                                              const float* __restrict__ De2,
                                              float* __restrict__ Dg0t, float* __restrict__ rs0,
                                              float* __restrict__ Det1, float* __restrict__ Det2,
                                              float* __restrict__ stats) {
    __shared__ float tile[32][33];
    int blk = blockIdx.x, tid = threadIdx.x;
    int r = tid >> 5, c = tid & 31;
    if (blk < 192) {  // D_eval1 [1024,165] -> Det1 [165][1024]
        int tq = blk & 31, tt = blk >> 5;
        int q0 = tq * 32, t0 = tt * 32;
        for (int rr = r; rr < 32; rr += 8) {
            int t = t0 + c;
            tile[rr][c] = (t < 165) ? De1[(q0 + rr) * 165 + t] : 0.f;
        }
        __syncthreads();
        for (int rr = r; rr < 32; rr += 8) {
            int t = t0 + rr;
            if (t < 165) Det1[t * QQ + q0 + c] = tile[c][rr];
        }
    } else if (blk < 288) {  // D_eval2 [1024,84] -> Det2 [84][1024]
        int i = blk - 192;
        int tq = i & 31, tt = i >> 5;
        int q0 = tq * 32, t0 = tt * 32;
        for (int rr = r; rr < 32; rr += 8) {
            int t = t0 + c;
            tile[rr][c] = (t < 84) ? De2[(q0 + rr) * 84 + t] : 0.f;
        }
        __syncthreads();
        for (int rr = r; rr < 32; rr += 8) {
            int t = t0 + rr;
            if (t < 84) Det2[t * QQ + q0 + c] = tile[c][rr];
        }
    } else if (blk < 352) {  // gather D_eval0[:, PIDX] -> Dg0t [36][1024]
        int i = blk - 288;
        int tq = i & 31, tj = i >> 5;
        int q0 = tq * 32, j0 = tj * 32;
        for (int rr = r; rr < 32; rr += 8) {
            int j = j0 + c;
            tile[rr][c] = (j < 36) ? De0[(q0 + rr) * 286 + PIDX[j]] : 0.f;
        }
        __syncthreads();
        for (int rr = r; rr < 32; rr += 8) {
            int j = j0 + rr;
            if (j < 36) Dg0t[j * QQ + q0 + c] = tile[c][rr];
        }
    } else if (blk < 608) {  // rowsum of D_eval0: one q per wave, 256 blocks, no serial loop
        int w = tid >> 6, lane = tid & 63;
        int q = (blk - 352) * 4 + w;
        float s = 0.f;
#pragma unroll
        for (int p = 0; p < 5; p++) {
            int idx = lane + p * 64;
            if (idx < 286) s += De0[q * 286 + idx];
        }
#pragma unroll
        for (int o = 32; o > 0; o >>= 1) s += __shfl_xor(s, o, 64);
        if (lane == 0) rs0[q] = s;
    } else {
        if (tid < 224) stats[tid] = 0.f;
    }
}

// ---------------- shells: partial sums over n-chunk; pbuf[zc][shell][b][s] ----------------
__global__ __launch_bounds__(256) void k_shells(const float* __restrict__ x,
                                                const float* __restrict__ dirs,
                                                float* __restrict__ pbuf) {
    __shared__ float4 lx[NN / NCH];
    int b = blockIdx.x, shell = blockIdx.y, zc = blockIdx.z;
    const float KL = 18.033688011112042f;  // log2(e)/SIGMA2, SIGMA2=0.08
    const float* xb = x + ((size_t)b * NN + zc * (NN / NCH)) * 3;
    for (int n = threadIdx.x; n < NN / NCH; n += 256) {
        float X = xb[n * 3 + 0];
        float Y = xb[n * 3 + 1];
        float Z = xb[n * 3 + 2];
        lx[n] = make_float4(X, Y, Z, -KL * (X * X + Y * Y + Z * Z));
    }
    __syncthreads();
    float r = (shell == 0) ? 0.4f : ((shell == 1) ? 0.8f : 1.2f);
    int s0 = threadIdx.x, s1 = threadIdx.x + 256;
    float cx0 = r * dirs[(shell * SS + s0) * 3 + 0];
    float cy0 = r * dirs[(shell * SS + s0) * 3 + 1];
    float cz0 = r * dirs[(shell * SS + s0) * 3 + 2];
    float cx1 = r * dirs[(shell * SS + s1) * 3 + 0];
    float cy1 = r * dirs[(shell * SS + s1) * 3 + 1];
    float cz1 = r * dirs[(shell * SS + s1) * 3 + 2];
    float base0 = -KL * (cx0 * cx0 + cy0 * cy0 + cz0 * cz0);
    float base1 = -KL * (cx1 * cx1 + cy1 * cy1 + cz1 * cz1);
    float cxs0 = 2.f * KL * cx0, cys0 = 2.f * KL * cy0, czs0 = 2.f * KL * cz0;
    float cxs1 = 2.f * KL * cx1, cys1 = 2.f * KL * cy1, czs1 = 2.f * KL * cz1;
    float a0 = 0.f, a1 = 0.f;
#pragma unroll 8
    for (int n = 0; n < NN / NCH; n++) {
        float4 p = lx[n];
        a0 += __builtin_amdgcn_exp2f(fmaf(cxs0, p.x, fmaf(cys0, p.y, fmaf(czs0, p.z, p.w + base0))));
        a1 += __builtin_amdgcn_exp2f(fmaf(cxs1, p.x, fmaf(cys1, p.y, fmaf(czs1, p.z, p.w + base1))));
    }
    float* o = pbuf + ((size_t)(zc * 3 + shell) * BB + b) * SS;
    o[s0] = a0;
    o[s1] = a1;
}

// ---------------- sh: per-b chunk reduce + SH projection + W0 mix -> lm_ws[b][36][16] ----------------
__global__ __launch_bounds__(512) void k_sh(const float* __restrict__ pbuf,
                                            const float* __restrict__ A_sh,
                                            const float* __restrict__ W0,
                                            float* __restrict__ lm_ws) {
    __shared__ float lf[3][SS];
    __shared__ float lsh[36][3];
    int b = blockIdx.x, tid = threadIdx.x;
    for (int i = tid; i < 3 * SS; i += 512) {
        int c = i / SS, s = i % SS;
        float v = 0.f;
#pragma unroll
        for (int zc = 0; zc < NCH; zc++) v += pbuf[((size_t)(zc * 3 + c) * BB + b) * SS + s];
        lf[c][s] = v * (1.0f / NN);
    }
    __syncthreads();
    int w = tid >> 6, lane = tid & 63;
    for (int p = w; p < 108; p += 8) {
        int j = p / 3, c = p % 3;
        const float* As = A_sh + j * SS;
        float a = 0.f;
#pragma unroll
        for (int k = 0; k < 8; k++) a = fmaf(lf[c][lane + 64 * k], As[lane + 64 * k], a);
#pragma unroll
        for (int o = 32; o > 0; o >>= 1) a += __shfl_xor(a, o, 64);
        if (lane == 0) lsh[j][c] = a;
    }
    __syncthreads();
    for (int i = tid; i < 576; i += 512) {
        int j = i >> 4, u = i & 15;
        float m = 0.f;
#pragma unroll
        for (int c = 0; c < 3; c++) m = fmaf(lsh[j][c], W0[c * 16 + u], m);
        lm_ws[b * 576 + i] = m;
    }
}

// ---------------- eval0q: sparse Wigner eval + bias*rowsum + fused stats ----------------
__global__ __launch_bounds__(256) void k_eval0q(const float* __restrict__ lm_ws,
                                                const float* __restrict__ b0,
                                                const float* __restrict__ Dg0t,
                                                const float* __restrict__ rs0,
                                                float* __restrict__ yq, float* __restrict__ stats) {
    __shared__ float llm[576];
    __shared__ float lred[4][32];
    int qc = blockIdx.x, b = blockIdx.y, tid = threadIdx.x;
    for (int i = tid; i < 576; i += 256) llm[i] = lm_ws[b * 576 + i];
    __syncthreads();
    int q = qc * 256 + tid;
    float acc[16];
#pragma unroll
    for (int u = 0; u < 16; u++) acc[u] = 0.f;
#pragma unroll 4
    for (int j = 0; j < 36; j++) {
        float d = Dg0t[j * QQ + q];
#pragma unroll
        for (int u = 0; u < 16; u++) acc[u] = fmaf(d, llm[j * 16 + u], acc[u]);
    }
    float rb = rs0[q];
#pragma unroll
    for (int u = 0; u < 16; u++) acc[u] = fmaf(b0[u], rb, acc[u]);
#pragma unroll
    for (int u = 0; u < 16; u++) yq[((size_t)b * 16 + u) * QQ + q] = acc[u];
    int lane = tid & 63, w = tid >> 6;
#pragma unroll
    for (int u = 0; u < 16; u++) {
        float v = acc[u], v2 = acc[u] * acc[u];
#pragma unroll
        for (int o = 32; o > 0; o >>= 1) {
            v += __shfl_xor(v, o, 64);
            v2 += __shfl_xor(v2, o, 64);
        }
        if (lane == 0) { lred[w][u] = v; lred[w][16 + u] = v2; }
    }
    __syncthreads();
    if (tid < 32) atomicAdd(&stats[tid], lred[0][tid] + lred[1][tid] + lred[2][tid] + lred[3][tid]);
}

// ---------------- coef as tiled GEMM: out[b][t][u] partials = D(TTxK) . act(Y)^T ----------------
template <int TT, int UU, int QKN>
__global__ __launch_bounds__(256) void k_coefG(const float* __restrict__ yq,
                                               const float* __restrict__ Dc,
                                               const float* __restrict__ stats,
                                               const float* __restrict__ g,
                                               const float* __restrict__ be,
                                               float* __restrict__ part) {
    constexpr int KC = QQ / QKN;
    __shared__ float lA[32][68];  // [kk][m]
    __shared__ float lB[32][68];  // [kk][n]
    __shared__ float lsu[UU], ltu[UU];
    int mt = blockIdx.x, nt = blockIdx.y, qk = blockIdx.z, tid = threadIdx.x;
    int m0 = mt * 64, n0 = nt * 64, k0 = qk * KC;
    if (tid < UU) {
        const float inv = 1.0f / (BB * QQ);
        float mm = stats[tid] * inv;
        float var = stats[UU + tid] * inv - mm * mm;
        float s = g[tid] * rsqrtf(fmaxf(var, 0.f) + 1e-3f);
        lsu[tid] = s;
        ltu[tid] = be[tid] - mm * s;
    }
    __syncthreads();
    int tg = tid >> 4, ug = tid & 15;
    int sr = tid >> 2;           // staged row 0..63
    int sk = (tid & 3) * 8;      // k sub-offset
    const float* drow = (m0 + sr < TT) ? (Dc + (size_t)(m0 + sr) * QQ) : nullptr;
    const float* yrow = yq + (size_t)(n0 + sr) * QQ;
    float su = lsu[(n0 + sr) % UU];
    float tu = ltu[(n0 + sr) % UU];
    float acc[4][4];
#pragma unroll
    for (int i = 0; i < 4; i++)
#pragma unroll
        for (int j = 0; j < 4; j++) acc[i][j] = 0.f;
    for (int kb = 0; kb < KC; kb += 32) {
        int kg = k0 + kb + sk;
#pragma unroll
        for (int jj = 0; jj < 8; jj++) {
            lA[sk + jj][sr] = drow ? drow[kg + jj] : 0.f;
            float bv = fmaf(yrow[kg + jj], su, tu);
            lB[sk + jj][sr] = (bv > 0.f) ? bv : 0.3f * bv;
        }
        __syncthreads();
#pragma unroll 2
        for (int kk = 0; kk < 32; kk++) {
            float4 a4 = *(const float4*)&lA[kk][tg * 4];
            float4 b4 = *(const float4*)&lB[kk][ug * 4];
#pragma unroll
            for (int i = 0; i < 4; i++) {
                float av = (&a4.x)[i];
                acc[i][0] = fmaf(av, b4.x, acc[i][0]);
                acc[i][1] = fmaf(av, b4.y, acc[i][1]);
                acc[i][2] = fmaf(av, b4.z, acc[i][2]);
                acc[i][3] = fmaf(av, b4.w, acc[i][3]);
            }
        }
        __syncthreads();
    }
    int n = n0 + ug * 4;
    int b = n / UU, u0 = n % UU;
#pragma unroll
    for (int i = 0; i < 4; i++) {
        int t = m0 + tg * 4 + i;
        if (t < TT)
            *(float4*)&part[(((size_t)qk * BB + b) * TT + t) * UU + u0] =
                make_float4(acc[i][0], acc[i][1], acc[i][2], acc[i][3]);
    }
}

// ---------------- generic eval: QKN partial-sum staging + mix(W,b) + Wigner eval + stats ----------------
template <int TT, int CC, int UU, int QKN>
__global__ __launch_bounds__(256) void k_eval(const float* __restrict__ part,
                                              const float* __restrict__ W, const float* __restrict__ bias,
                                              const float* __restrict__ Det,
                                              float* __restrict__ yq, float* __restrict__ stats) {
    __shared__ float lyt[TT * CC];
    __shared__ float lym[TT * 16];
    __shared__ float lred[4][32];
    int qc = blockIdx.x, b = blockIdx.y, uz = blockIdx.z * 16, tid = threadIdx.x;
    for (int i = tid; i < TT * CC; i += 256) {
        float v = 0.f;
#pragma unroll
        for (int k = 0; k < QKN; k++) v += part[((size_t)k * BB + b) * TT * CC + i];
        lyt[i] = v;
    }
    __syncthreads();
    for (int e = tid; e < TT * 16; e += 256) {
        int t = e >> 4, ul = e & 15, u = uz + ul;
        float m = bias[u];
#pragma unroll
        for (int c = 0; c < CC; c++) m = fmaf(lyt[t * CC + c], W[c * UU + u], m);
        lym[e] = m;
    }
    __syncthreads();
    int q = qc * 256 + tid;
    float acc[16];
#pragma unroll
    for (int u = 0; u < 16; u++) acc[u] = 0.f;
#pragma unroll 4
    for (int t = 0; t < TT; t++) {
        float d = Det[t * QQ + q];
#pragma unroll
        for (int u = 0; u < 16; u++) acc[u] = fmaf(d, lym[t * 16 + u], acc[u]);
    }
#pragma unroll
    for (int u = 0; u < 16; u++) yq[((size_t)b * UU + uz + u) * QQ + q] = acc[u];
    int lane = tid & 63, w = tid >> 6;
#pragma unroll
    for (int u = 0; u < 16; u++) {
        float v = acc[u], v2 = acc[u] * acc[u];
#pragma unroll
        for (int o = 32; o > 0; o >>= 1) {
            v += __shfl_xor(v, o, 64);
            v2 += __shfl_xor(v2, o, 64);
        }
        if (lane == 0) { lred[w][u] = v; lred[w][16 + u] = v2; }
    }
    __syncthreads();
    if (tid < 32) {
        float s = lred[0][tid] + lred[1][tid] + lred[2][tid] + lred[3][tid];
        int idx = (tid < 16) ? (uz + tid) : (UU + uz + tid - 16);
        atomicAdd(&stats[idx], s);
    }
}

// ---------------- degree-wise norms: LDS-staged partial sum, then norms ----------------
__global__ __launch_bounds__(256) void k_norms(const float* __restrict__ part, float* __restrict__ ht0) {
    __shared__ float ly[84][64];
    int b = blockIdx.x, tid = threadIdx.x;
    for (int i = tid; i < 84 * 64; i += 256) {
        float v = 0.f;
#pragma unroll
        for (int k = 0; k < QKN3; k++) v += part[((size_t)k * BB + b) * (84 * 64) + i];
        ((float*)ly)[i] = v;
    }
    __syncthreads();
    int blk = tid >> 6, u = tid & 63;
    const int offs[4] = {0, 1, 10, 35};
    const int ends[4] = {1, 10, 35, 84};
    float a = 0.f;
    for (int t = offs[blk]; t < ends[blk]; t++) {
        float v = ly[t][u];
        a = fmaf(v, v, a);
    }
    ht0[(blk * 64 + u) * BB + b] = sqrtf(fmaxf(a, 0.f));
}

// ---------------- fc + batch-BN + relu: one j per block, 4-way k-split, LDS+shfl reduce ----------------
template <int K, int J>
__global__ __launch_bounds__(256) void k_fc(const float* __restrict__ in, const float* __restrict__ W,
                                            const float* __restrict__ bias, const float* __restrict__ g,
                                            const float* __restrict__ be, float* __restrict__ out) {
    __shared__ float red[4][64];
    int j = blockIdx.x;
    int b = threadIdx.x & 63, kq = threadIdx.x >> 6;
    float a = 0.f;
    for (int k = kq; k < K; k += 4)
        a = fmaf(in[k * BB + b], W[(size_t)k * J + j], a);
    red[kq][b] = a;
    __syncthreads();
    if (kq == 0) {
        float acc = red[0][b] + red[1][b] + red[2][b] + red[3][b] + bias[j];
        float s1 = acc, s2 = acc * acc;
#pragma unroll
        for (int o = 32; o > 0; o >>= 1) {
            s1 += __shfl_xor(s1, o, 64);
            s2 += __shfl_xor(s2, o, 64);
        }
        float m = s1 * (1.0f / 64.f);
        float var = s2 * (1.0f / 64.f) - m * m;
        float sc = g[j] * rsqrtf(fmaxf(var, 0.f) + 1e-3f);
        float v = (acc - m) * sc + be[j];
        out[j * BB + b] = fmaxf(v, 0.f);
    }
}

// ---------------- output layer + softmax: 4-way k-split + LDS reduce ----------------
__global__ __launch_bounds__(256) void k_out(const float* __restrict__ ht2, const float* __restrict__ Wout,
                                             const float* __restrict__ bout, float* __restrict__ outp) {
    __shared__ float red[4][64];
    __shared__ float sm[64];
    int b = blockIdx.x;
    int o = threadIdx.x & 63, kq = threadIdx.x >> 6;
    float a = 0.f;
    if (o < 40) {
        for (int k = kq; k < 256; k += 4)
            a = fmaf(ht2[k * BB + b], Wout[k * 40 + o], a);
    }
    red[kq][o] = a;
    __syncthreads();
    if (kq == 0) {
        float acc = red[0][o] + red[1][o] + red[2][o] + red[3][o] + ((o < 40) ? bout[o] : 0.f);
        sm[o] = (o < 40) ? acc : -3.0e38f;
        __syncthreads();
        for (int s = 32; s > 0; s >>= 1) {
            if (o < s) sm[o] = fmaxf(sm[o], sm[o + s]);
            __syncthreads();
        }
        float m = sm[0];
        __syncthreads();
        const float L2E = 1.4426950408889634f;
        float e = (o < 40) ? exp2f((acc - m) * L2E) : 0.f;
        sm[o] = e;
        __syncthreads();
        for (int s = 32; s > 0; s >>= 1) {
            if (o < s) sm[o] += sm[o + s];
            __syncthreads();
        }
        if (o < 40) outp[b * 40 + o] = e / sm[0];
    }
}

// ---------------- workspace layout (float offsets) ----------------
#define OFF_PBUF 0          // 8*3*64*512 = 786432
#define OFF_DG0T 786432     // 36864
#define OFF_RS0 823296      // 1024
#define OFF_DET1 824320     // 168960
#define OFF_DET2 993280     // 86016
#define OFF_LM 1079296      // 36864
#define OFF_YQ 1116160      // 4194304
#define OFF_PART 5310464    // 1376256
#define OFF_HT0 6686720     // 16384
#define OFF_HT1 6703104     // 32768
#define OFF_HT2 6735872     // 16384
#define OFF_STATS 6752256   // 224

extern "C" void kernel_launch(void* const* d_in, const int* in_sizes, int n_in,
                              void* d_out, int out_size, void* d_ws, size_t ws_size,
                              hipStream_t stream) {
    const float* x = (const float*)d_in[0];
    const float* shell_dirs = (const float*)d_in[1];
    const float* A_sh = (const float*)d_in[2];
    const float* D_eval0 = (const float*)d_in[3];
    const float* D_eval1 = (const float*)d_in[4];
    const float* D_eval2 = (const float*)d_in[5];
    const float* D_coef1 = (const float*)d_in[6];
    const float* D_coef2 = (const float*)d_in[7];
    const float* D_coef_last = (const float*)d_in[8];
    const float* W0 = (const float*)d_in[9];
    const float* b0 = (const float*)d_in[10];
    const float* W1 = (const float*)d_in[11];
    const float* b1 = (const float*)d_in[12];
    const float* W2 = (const float*)d_in[13];
    const float* b2 = (const float*)d_in[14];
    const float* g0 = (const float*)d_in[15];
    const float* be0 = (const float*)d_in[16];
    const float* g1 = (const float*)d_in[17];
    const float* be1 = (const float*)d_in[18];
    const float* g2 = (const float*)d_in[19];
    const float* be2 = (const float*)d_in[20];
    const float* Wfc1 = (const float*)d_in[21];
    const float* bfc1 = (const float*)d_in[22];
    const float* gfc1 = (const float*)d_in[23];
    const float* befc1 = (const float*)d_in[24];
    const float* Wfc2 = (const float*)d_in[25];
    const float* bfc2 = (const float*)d_in[26];
    const float* gfc2 = (const float*)d_in[27];
    const float* befc2 = (const float*)d_in[28];
    const float* Wout = (const float*)d_in[29];
    const float* bout = (const float*)d_in[30];
    float* out = (float*)d_out;

    float* ws = (float*)d_ws;
    float* pbuf = ws + OFF_PBUF;
    float* Dg0t = ws + OFF_DG0T;
    float* rs0 = ws + OFF_RS0;
    float* Det1 = ws + OFF_DET1;
    float* Det2 = ws + OFF_DET2;
    float* lm_ws = ws + OFF_LM;
    float* yq = ws + OFF_YQ;
    float* part = ws + OFF_PART;
    float* ht0 = ws + OFF_HT0;
    float* ht1 = ws + OFF_HT1;
    float* ht2 = ws + OFF_HT2;
    float* stats = ws + OFF_STATS;
    float* stats0 = stats;       // 32
    float* stats1 = stats + 32;  // 64
    float* stats2 = stats + 96;  // 128

    k_prep<<<609, 256, 0, stream>>>(D_eval0, D_eval1, D_eval2, Dg0t, rs0, Det1, Det2, stats);
    k_shells<<<dim3(BB, 3, NCH), 256, 0, stream>>>(x, shell_dirs, pbuf);
    k_sh<<<BB, 512, 0, stream>>>(pbuf, A_sh, W0, lm_ws);
    k_eval0q<<<dim3(4, BB), 256, 0, stream>>>(lm_ws, b0, Dg0t, rs0, yq, stats0);
    k_coefG<165, 16, 8><<<dim3(3, 16, 8), 256, 0, stream>>>(yq, D_coef1, stats0, g0, be0, part);
    k_eval<165, 16, 32, 8><<<dim3(4, BB, 2), 256, 0, stream>>>(part, W1, b1, Det1, yq, stats1);
    k_coefG<84, 32, 8><<<dim3(2, 32, 8), 256, 0, stream>>>(yq, D_coef2, stats1, g1, be1, part);
    k_eval<84, 32, 64, 8><<<dim3(4, BB, 4), 256, 0, stream>>>(part, W2, b2, Det2, yq, stats2);
    k_coefG<84, 64, QKN3><<<dim3(2, 64, QKN3), 256, 0, stream>>>(yq, D_coef_last, stats2, g2, be2, part);
    k_norms<<<BB, 256, 0, stream>>>(part, ht0);
    k_fc<256, 512><<<512, 256, 0, stream>>>(ht0, Wfc1, bfc1, gfc1, befc1, ht1);
    k_fc<512, 256><<<256, 256, 0, stream>>>(ht1, Wfc2, bfc2, gfc2, befc2, ht2);
    k_out<<<BB, 256, 0, stream>>>(ht2, Wout, bout, out);
}

// Round 9
// 395.169 us; speedup vs baseline: 1.3702x; 1.0845x over previous
//
#include <hip/hip_runtime.h>
#include <hip/hip_bf16.h>

#define BB 64
#define NN 2048
#define QQ 1024
#define SS 512
#define NCH 8

#define NZERO 685056  // yt1+yt2+yt3 floats (contiguous)
#define PREPB 1278    // prep blocks inside merged kernel

__device__ const int PIDX[36] = {
    0, 2, 5, 8, 12, 17, 22, 27, 32, 38, 45, 52, 59, 66, 73, 80,
    88, 97, 106, 115, 124, 133, 142, 151, 160,
    170, 181, 192, 203, 214, 225, 236, 247, 258, 269, 280};

// ---------------- merged prep + shells ----------------
__global__ __launch_bounds__(256) void k_preshell(
    const float* __restrict__ De0, const float* __restrict__ De1, const float* __restrict__ De2,
    float* __restrict__ Dg0t, float* __restrict__ rs0,
    float* __restrict__ Det1, float* __restrict__ Det2,
    float* __restrict__ stats, float* __restrict__ ytz,
    const float* __restrict__ x, const float* __restrict__ dirs, float* __restrict__ pbuf) {
    __shared__ float tile[32][33];
    __shared__ float4 lx[NN / NCH];
    int blk = blockIdx.x, tid = threadIdx.x;
    if (blk < PREPB) {
        int r = tid >> 5, c = tid & 31;
        if (blk < 192) {  // D_eval1 -> Det1 [165][1024]
            int tq = blk & 31, tt = blk >> 5;
            int q0 = tq * 32, t0 = tt * 32;
            for (int rr = r; rr < 32; rr += 8) {
                int t = t0 + c;
                tile[rr][c] = (t < 165) ? De1[(q0 + rr) * 165 + t] : 0.f;
            }
            __syncthreads();
            for (int rr = r; rr < 32; rr += 8) {
                int t = t0 + rr;
                if (t < 165) Det1[t * QQ + q0 + c] = tile[c][rr];
            }
        } else if (blk < 288) {  // D_eval2 -> Det2 [84][1024]
            int i = blk - 192;
            int tq = i & 31, tt = i >> 5;
            int q0 = tq * 32, t0 = tt * 32;
            for (int rr = r; rr < 32; rr += 8) {
                int t = t0 + c;
                tile[rr][c] = (t < 84) ? De2[(q0 + rr) * 84 + t] : 0.f;
            }
            __syncthreads();
            for (int rr = r; rr < 32; rr += 8) {
                int t = t0 + rr;
                if (t < 84) Det2[t * QQ + q0 + c] = tile[c][rr];
            }
        } else if (blk < 352) {  // gather D_eval0[:, PIDX] -> Dg0t [36][1024]
            int i = blk - 288;
            int tq = i & 31, tj = i >> 5;
            int q0 = tq * 32, j0 = tj * 32;
            for (int rr = r; rr < 32; rr += 8) {
                int j = j0 + c;
                tile[rr][c] = (j < 36) ? De0[(q0 + rr) * 286 + PIDX[j]] : 0.f;
            }
            __syncthreads();
            for (int rr = r; rr < 32; rr += 8) {
                int j = j0 + rr;
                if (j < 36) Dg0t[j * QQ + q0 + c] = tile[c][rr];
            }
        } else if (blk < 608) {  // rowsum: one q per wave
            int w = tid >> 6, lane = tid & 63;
            int q = (blk - 352) * 4 + w;
            float s = 0.f;
#pragma unroll
            for (int p = 0; p < 5; p++) {
                int idx = lane + p * 64;
                if (idx < 286) s += De0[q * 286 + idx];
            }
#pragma unroll
            for (int o = 32; o > 0; o >>= 1) s += __shfl_xor(s, o, 64);
            if (lane == 0) rs0[q] = s;
        } else if (blk == 608) {
            if (tid < 224) stats[tid] = 0.f;
        } else {  // zero yt region (atomic accumulation targets)
            int idx = ((blk - 609) * 256 + tid) * 4;
            if (idx < NZERO) *(float4*)&ytz[idx] = make_float4(0.f, 0.f, 0.f, 0.f);
        }
        return;
    }
    // ---- shells path ----
    int s = blk - PREPB;
    int b = s & 63, rest = s >> 6;
    int shell = rest % 3, zc = rest / 3;
    const float KL = 18.033688011112042f;  // log2(e)/SIGMA2, SIGMA2=0.08
    const float* xb = x + ((size_t)b * NN + zc * (NN / NCH)) * 3;
    for (int n = tid; n < NN / NCH; n += 256) {
        float X = xb[n * 3 + 0];
        float Y = xb[n * 3 + 1];
        float Z = xb[n * 3 + 2];
        lx[n] = make_float4(X, Y, Z, -KL * (X * X + Y * Y + Z * Z));
    }
    __syncthreads();
    float r = (shell == 0) ? 0.4f : ((shell == 1) ? 0.8f : 1.2f);
    int s0 = tid, s1 = tid + 256;
    float cx0 = r * dirs[(shell * SS + s0) * 3 + 0];
    float cy0 = r * dirs[(shell * SS + s0) * 3 + 1];
    float cz0 = r * dirs[(shell * SS + s0) * 3 + 2];
    float cx1 = r * dirs[(shell * SS + s1) * 3 + 0];
    float cy1 = r * dirs[(shell * SS + s1) * 3 + 1];
    float cz1 = r * dirs[(shell * SS + s1) * 3 + 2];
    float base0 = -KL * (cx0 * cx0 + cy0 * cy0 + cz0 * cz0);
    float base1 = -KL * (cx1 * cx1 + cy1 * cy1 + cz1 * cz1);
    float cxs0 = 2.f * KL * cx0, cys0 = 2.f * KL * cy0, czs0 = 2.f * KL * cz0;
    float cxs1 = 2.f * KL * cx1, cys1 = 2.f * KL * cy1, czs1 = 2.f * KL * cz1;
    float a0 = 0.f, a1 = 0.f;
#pragma unroll 8
    for (int n = 0; n < NN / NCH; n++) {
        float4 p = lx[n];
        a0 += __builtin_amdgcn_exp2f(fmaf(cxs0, p.x, fmaf(cys0, p.y, fmaf(czs0, p.z, p.w + base0))));
        a1 += __builtin_amdgcn_exp2f(fmaf(cxs1, p.x, fmaf(cys1, p.y, fmaf(czs1, p.z, p.w + base1))));
    }
    float* o = pbuf + ((size_t)(zc * 3 + shell) * BB + b) * SS;
    o[s0] = a0;
    o[s1] = a1;
}

// ---------------- sh: per-b chunk reduce + SH projection + W0 mix (1024 thr) ----------------
__global__ __launch_bounds__(1024) void k_sh(const float* __restrict__ pbuf,
                                             const float* __restrict__ A_sh,
                                             const float* __restrict__ W0,
                                             float* __restrict__ lm_ws) {
    __shared__ float lf[3][SS];
    __shared__ float lsh[36][3];
    int b = blockIdx.x, tid = threadIdx.x;
    for (int i = tid; i < 3 * SS; i += 1024) {
        int c = i / SS, s = i % SS;
        float v = 0.f;
#pragma unroll
        for (int zc = 0; zc < NCH; zc++) v += pbuf[((size_t)(zc * 3 + c) * BB + b) * SS + s];
        lf[c][s] = v * (1.0f / NN);
    }
    __syncthreads();
    int w = tid >> 6, lane = tid & 63;
    for (int p = w; p < 108; p += 16) {
        int j = p / 3, c = p % 3;
        const float* As = A_sh + j * SS;
        float a = 0.f;
#pragma unroll
        for (int k = 0; k < 8; k++) a = fmaf(lf[c][lane + 64 * k], As[lane + 64 * k], a);
#pragma unroll
        for (int o = 32; o > 0; o >>= 1) a += __shfl_xor(a, o, 64);
        if (lane == 0) lsh[j][c] = a;
    }
    __syncthreads();
    for (int i = tid; i < 576; i += 1024) {
        int j = i >> 4, u = i & 15;
        float m = 0.f;
#pragma unroll
        for (int c = 0; c < 3; c++) m = fmaf(lsh[j][c], W0[c * 16 + u], m);
        lm_ws[b * 576 + i] = m;
    }
}

// ---------------- eval0q: sparse Wigner eval + bias*rowsum + fused stats ----------------
__global__ __launch_bounds__(256) void k_eval0q(const float* __restrict__ lm_ws,
                                                const float* __restrict__ b0,
                                                const float* __restrict__ Dg0t,
                                                const float* __restrict__ rs0,
                                                float* __restrict__ yq, float* __restrict__ stats) {
    __shared__ float llm[576];
    __shared__ float lred[4][32];
    int qc = blockIdx.x, b = blockIdx.y, tid = threadIdx.x;
    for (int i = tid; i < 576; i += 256) llm[i] = lm_ws[b * 576 + i];
    __syncthreads();
    int q = qc * 256 + tid;
    float acc[16];
#pragma unroll
    for (int u = 0; u < 16; u++) acc[u] = 0.f;
#pragma unroll 4
    for (int j = 0; j < 36; j++) {
        float d = Dg0t[j * QQ + q];
#pragma unroll
        for (int u = 0; u < 16; u++) acc[u] = fmaf(d, llm[j * 16 + u], acc[u]);
    }
    float rb = rs0[q];
#pragma unroll
    for (int u = 0; u < 16; u++) acc[u] = fmaf(b0[u], rb, acc[u]);
#pragma unroll
    for (int u = 0; u < 16; u++) yq[((size_t)b * 16 + u) * QQ + q] = acc[u];
    int lane = tid & 63, w = tid >> 6;
#pragma unroll
    for (int u = 0; u < 16; u++) {
        float v = acc[u], v2 = acc[u] * acc[u];
#pragma unroll
        for (int o = 32; o > 0; o >>= 1) {
            v += __shfl_xor(v, o, 64);
            v2 += __shfl_xor(v2, o, 64);
        }
        if (lane == 0) { lred[w][u] = v; lred[w][16 + u] = v2; }
    }
    __syncthreads();
    if (tid < 32) atomicAdd(&stats[tid], lred[0][tid] + lred[1][tid] + lred[2][tid] + lred[3][tid]);
}

// ---------------- coef GEMM: float4-coalesced staging, atomicAdd into yt ----------------
template <int TT, int UU, int QKN>
__global__ __launch_bounds__(256) void k_coefG(const float* __restrict__ yq,
                                               const float* __restrict__ Dc,
                                               const float* __restrict__ stats,
                                               const float* __restrict__ g,
                                               const float* __restrict__ be,
                                               float* __restrict__ yt) {
    constexpr int KC = QQ / QKN;
    __shared__ float lA[32][68];
    __shared__ float lB[32][68];
    __shared__ float lsu[UU], ltu[UU];
    int mt = blockIdx.x, nt = blockIdx.y, qk = blockIdx.z, tid = threadIdx.x;
    int m0 = mt * 64, n0 = nt * 64, k0 = qk * KC;
    if (tid < UU) {
        const float inv = 1.0f / (BB * QQ);
        float mm = stats[tid] * inv;
        float var = stats[UU + tid] * inv - mm * mm;
        float s = g[tid] * rsqrtf(fmaxf(var, 0.f) + 1e-3f);
        lsu[tid] = s;
        ltu[tid] = be[tid] - mm * s;
    }
    __syncthreads();
    int r = tid >> 2;        // staged row 0..63
    int f = (tid & 3) * 4;   // k sub-offset {0,4,8,12}
    bool mok = (m0 + r) < TT;
    const float* arow = Dc + (size_t)(mok ? (m0 + r) : 0) * QQ;
    const float* brow = yq + (size_t)(n0 + r) * QQ;
    float su = lsu[(n0 + r) % UU], tu = ltu[(n0 + r) % UU];
    int tg = tid >> 4, ug = tid & 15;
    float acc[4][4];
#pragma unroll
    for (int i = 0; i < 4; i++)
#pragma unroll
        for (int j = 0; j < 4; j++) acc[i][j] = 0.f;
    for (int kb = 0; kb < KC; kb += 32) {
        int kg = k0 + kb;
#pragma unroll
        for (int p = 0; p < 2; p++) {
            int ko = f + p * 16;
            float4 a4 = make_float4(0.f, 0.f, 0.f, 0.f);
            if (mok) a4 = *(const float4*)(arow + kg + ko);
            float4 b4 = *(const float4*)(brow + kg + ko);
#pragma unroll
            for (int i = 0; i < 4; i++) {
                float v = fmaf((&b4.x)[i], su, tu);
                lA[ko + i][r] = (&a4.x)[i];
                lB[ko + i][r] = (v > 0.f) ? v : 0.3f * v;
            }
        }
        __syncthreads();
#pragma unroll 2
        for (int kk = 0; kk < 32; kk++) {
            float4 a4 = *(const float4*)&lA[kk][tg * 4];
            float4 b4 = *(const float4*)&lB[kk][ug * 4];
#pragma unroll
            for (int i = 0; i < 4; i++) {
                float av = (&a4.x)[i];
                acc[i][0] = fmaf(av, b4.x, acc[i][0]);
                acc[i][1] = fmaf(av, b4.y, acc[i][1]);
                acc[i][2] = fmaf(av, b4.z, acc[i][2]);
                acc[i][3] = fmaf(av, b4.w, acc[i][3]);
            }
        }
        __syncthreads();
    }
    int n = n0 + ug * 4;
    int b = n / UU, u0 = n % UU;
#pragma unroll
    for (int i = 0; i < 4; i++) {
        int t = m0 + tg * 4 + i;
        if (t < TT) {
            float* dst = &yt[((size_t)b * TT + t) * UU + u0];
#pragma unroll
            for (int jx = 0; jx < 4; jx++) atomicAdd(dst + jx, acc[i][jx]);
        }
    }
}

// ---------------- generic eval: mix(W,b) + Wigner eval + fused stats ----------------
template <int TT, int CC, int UU>
__global__ __launch_bounds__(256) void k_eval(const float* __restrict__ yt,
                                              const float* __restrict__ W, const float* __restrict__ bias,
                                              const float* __restrict__ Det,
                                              float* __restrict__ yq, float* __restrict__ stats) {
    __shared__ float lyt[TT * CC];
    __shared__ float lym[TT * 16];
    __shared__ float lred[4][32];
    int qc = blockIdx.x, b = blockIdx.y, uz = blockIdx.z * 16, tid = threadIdx.x;
    for (int i = tid; i < TT * CC; i += 256) lyt[i] = yt[(size_t)b * TT * CC + i];
    __syncthreads();
    for (int e = tid; e < TT * 16; e += 256) {
        int t = e >> 4, ul = e & 15, u = uz + ul;
        float m = bias[u];
#pragma unroll
        for (int c = 0; c < CC; c++) m = fmaf(lyt[t * CC + c], W[c * UU + u], m);
        lym[e] = m;
    }
    __syncthreads();
    int q = qc * 256 + tid;
    float acc[16];
#pragma unroll
    for (int u = 0; u < 16; u++) acc[u] = 0.f;
#pragma unroll 4
    for (int t = 0; t < TT; t++) {
        float d = Det[t * QQ + q];
#pragma unroll
        for (int u = 0; u < 16; u++) acc[u] = fmaf(d, lym[t * 16 + u], acc[u]);
    }
#pragma unroll
    for (int u = 0; u < 16; u++) yq[((size_t)b * UU + uz + u) * QQ + q] = acc[u];
    int lane = tid & 63, w = tid >> 6;
#pragma unroll
    for (int u = 0; u < 16; u++) {
        float v = acc[u], v2 = acc[u] * acc[u];
#pragma unroll
        for (int o = 32; o > 0; o >>= 1) {
            v += __shfl_xor(v, o, 64);
            v2 += __shfl_xor(v2, o, 64);
        }
        if (lane == 0) { lred[w][u] = v; lred[w][16 + u] = v2; }
    }
    __syncthreads();
    if (tid < 32) {
        float s = lred[0][tid] + lred[1][tid] + lred[2][tid] + lred[3][tid];
        int idx = (tid < 16) ? (uz + tid) : (UU + uz + tid - 16);
        atomicAdd(&stats[idx], s);
    }
}

// ---------------- degree-wise norms: grid (b, blk), 4-way t-split ----------------
__global__ __launch_bounds__(256) void k_norms(const float* __restrict__ yt3, float* __restrict__ ht0) {
    __shared__ float red[4][64];
    int b = blockIdx.x, blk = blockIdx.y;
    int tq = threadIdx.x >> 6, u = threadIdx.x & 63;
    const int offs[4] = {0, 1, 10, 35};
    const int ends[4] = {1, 10, 35, 84};
    float a = 0.f;
    for (int t = offs[blk] + tq; t < ends[blk]; t += 4) {
        float v = yt3[((size_t)b * 84 + t) * 64 + u];
        a = fmaf(v, v, a);
    }
    red[tq][u] = a;
    __syncthreads();
    if (tq == 0) {
        float s = red[0][u] + red[1][u] + red[2][u] + red[3][u];
        ht0[(blk * 64 + u) * BB + b] = sqrtf(fmaxf(s, 0.f));
    }
}

// ---------------- fc + batch-BN + relu: 8-way k-split, 4-acc unroll ----------------
template <int K, int J>
__global__ __launch_bounds__(512) void k_fc(const float* __restrict__ in, const float* __restrict__ W,
                                            const float* __restrict__ bias, const float* __restrict__ g,
                                            const float* __restrict__ be, float* __restrict__ out) {
    __shared__ float red[8][64];
    int j = blockIdx.x;
    int b = threadIdx.x & 63, kq = threadIdx.x >> 6;  // 0..7
    constexpr int KS = K / 8;
    int kbeg = kq * KS;
    float a0 = 0.f, a1 = 0.f, a2 = 0.f, a3 = 0.f;
#pragma unroll 4
    for (int k = kbeg; k < kbeg + KS; k += 4) {
        a0 = fmaf(in[k * BB + b], W[(size_t)k * J + j], a0);
        a1 = fmaf(in[(k + 1) * BB + b], W[(size_t)(k + 1) * J + j], a1);
        a2 = fmaf(in[(k + 2) * BB + b], W[(size_t)(k + 2) * J + j], a2);
        a3 = fmaf(in[(k + 3) * BB + b], W[(size_t)(k + 3) * J + j], a3);
    }
    red[kq][b] = (a0 + a1) + (a2 + a3);
    __syncthreads();
    if (kq == 0) {
        float acc = bias[j];
#pragma unroll
        for (int i = 0; i < 8; i++) acc += red[i][b];
        float s1 = acc, s2 = acc * acc;
#pragma unroll
        for (int o = 32; o > 0; o >>= 1) {
            s1 += __shfl_xor(s1, o, 64);
            s2 += __shfl_xor(s2, o, 64);
        }
        float m = s1 * (1.0f / 64.f);
        float var = s2 * (1.0f / 64.f) - m * m;
        float sc = g[j] * rsqrtf(fmaxf(var, 0.f) + 1e-3f);
        float v = (acc - m) * sc + be[j];
        out[j * BB + b] = fmaxf(v, 0.f);
    }
}

// ---------------- output layer + softmax: 4-way k-split, 4-acc unroll ----------------
__global__ __launch_bounds__(256) void k_out(const float* __restrict__ ht2, const float* __restrict__ Wout,
                                             const float* __restrict__ bout, float* __restrict__ outp) {
    __shared__ float red[4][64];
    __shared__ float sm[64];
    int b = blockIdx.x;
    int o = threadIdx.x & 63, kq = threadIdx.x >> 6;
    float a0 = 0.f, a1 = 0.f, a2 = 0.f, a3 = 0.f;
    int kbeg = kq * 64;
    if (o < 40) {
#pragma unroll 4
        for (int k = kbeg; k < kbeg + 64; k += 4) {
            a0 = fmaf(ht2[k * BB + b], Wout[k * 40 + o], a0);
            a1 = fmaf(ht2[(k + 1) * BB + b], Wout[(k + 1) * 40 + o], a1);
            a2 = fmaf(ht2[(k + 2) * BB + b], Wout[(k + 2) * 40 + o], a2);
            a3 = fmaf(ht2[(k + 3) * BB + b], Wout[(k + 3) * 40 + o], a3);
        }
    }
    red[kq][o] = (a0 + a1) + (a2 + a3);
    __syncthreads();
    if (kq == 0) {
        float acc = red[0][o] + red[1][o] + red[2][o] + red[3][o] + ((o < 40) ? bout[o] : 0.f);
        sm[o] = (o < 40) ? acc : -3.0e38f;
        __syncthreads();
        for (int s = 32; s > 0; s >>= 1) {
            if (o < s) sm[o] = fmaxf(sm[o], sm[o + s]);
            __syncthreads();
        }
        float m = sm[0];
        __syncthreads();
        const float L2E = 1.4426950408889634f;
        float e = (o < 40) ? exp2f((acc - m) * L2E) : 0.f;
        sm[o] = e;
        __syncthreads();
        for (int s = 32; s > 0; s >>= 1) {
            if (o < s) sm[o] += sm[o + s];
            __syncthreads();
        }
        if (o < 40) outp[b * 40 + o] = e / sm[0];
    }
}

// ---------------- workspace layout (float offsets) ----------------
#define OFF_PBUF 0          // 786432
#define OFF_DG0T 786432     // 36864
#define OFF_RS0 823296      // 1024
#define OFF_DET1 824320     // 168960
#define OFF_DET2 993280     // 86016
#define OFF_LM 1079296      // 36864
#define OFF_YQ 1116160      // 4194304
#define OFF_YT 5310464      // 685056 (yt1|yt2|yt3 contiguous, atomic targets)
#define OFF_HT0 5995520     // 16384
#define OFF_HT1 6011904     // 32768
#define OFF_HT2 6044672     // 16384
#define OFF_STATS 6061056   // 224

extern "C" void kernel_launch(void* const* d_in, const int* in_sizes, int n_in,
                              void* d_out, int out_size, void* d_ws, size_t ws_size,
                              hipStream_t stream) {
    const float* x = (const float*)d_in[0];
    const float* shell_dirs = (const float*)d_in[1];
    const float* A_sh = (const float*)d_in[2];
    const float* D_eval0 = (const float*)d_in[3];
    const float* D_eval1 = (const float*)d_in[4];
    const float* D_eval2 = (const float*)d_in[5];
    const float* D_coef1 = (const float*)d_in[6];
    const float* D_coef2 = (const float*)d_in[7];
    const float* D_coef_last = (const float*)d_in[8];
    const float* W0 = (const float*)d_in[9];
    const float* b0 = (const float*)d_in[10];
    const float* W1 = (const float*)d_in[11];
    const float* b1 = (const float*)d_in[12];
    const float* W2 = (const float*)d_in[13];
    const float* b2 = (const float*)d_in[14];
    const float* g0 = (const float*)d_in[15];
    const float* be0 = (const float*)d_in[16];
    const float* g1 = (const float*)d_in[17];
    const float* be1 = (const float*)d_in[18];
    const float* g2 = (const float*)d_in[19];
    const float* be2 = (const float*)d_in[20];
    const float* Wfc1 = (const float*)d_in[21];
    const float* bfc1 = (const float*)d_in[22];
    const float* gfc1 = (const float*)d_in[23];
    const float* befc1 = (const float*)d_in[24];
    const float* Wfc2 = (const float*)d_in[25];
    const float* bfc2 = (const float*)d_in[26];
    const float* gfc2 = (const float*)d_in[27];
    const float* befc2 = (const float*)d_in[28];
    const float* Wout = (const float*)d_in[29];
    const float* bout = (const float*)d_in[30];
    float* out = (float*)d_out;

    float* ws = (float*)d_ws;
    float* pbuf = ws + OFF_PBUF;
    float* Dg0t = ws + OFF_DG0T;
    float* rs0 = ws + OFF_RS0;
    float* Det1 = ws + OFF_DET1;
    float* Det2 = ws + OFF_DET2;
    float* lm_ws = ws + OFF_LM;
    float* yq = ws + OFF_YQ;
    float* yt1 = ws + OFF_YT;            // 165*16*64 = 168960
    float* yt2 = yt1 + 168960;           // 84*32*64 = 172032
    float* yt3 = yt2 + 172032;           // 84*64*64 = 344064
    float* ht0 = ws + OFF_HT0;
    float* ht1 = ws + OFF_HT1;
    float* ht2 = ws + OFF_HT2;
    float* stats = ws + OFF_STATS;
    float* stats0 = stats;       // 32
    float* stats1 = stats + 32;  // 64
    float* stats2 = stats + 96;  // 128

    k_preshell<<<PREPB + BB * 3 * NCH, 256, 0, stream>>>(
        D_eval0, D_eval1, D_eval2, Dg0t, rs0, Det1, Det2, stats, yt1, x, shell_dirs, pbuf);
    k_sh<<<BB, 1024, 0, stream>>>(pbuf, A_sh, W0, lm_ws);
    k_eval0q<<<dim3(4, BB), 256, 0, stream>>>(lm_ws, b0, Dg0t, rs0, yq, stats0);
    k_coefG<165, 16, 16><<<dim3(3, 16, 16), 256, 0, stream>>>(yq, D_coef1, stats0, g0, be0, yt1);
    k_eval<165, 16, 32><<<dim3(4, BB, 2), 256, 0, stream>>>(yt1, W1, b1, Det1, yq, stats1);
    k_coefG<84, 32, 8><<<dim3(2, 32, 8), 256, 0, stream>>>(yq, D_coef2, stats1, g1, be1, yt2);
    k_eval<84, 32, 64><<<dim3(4, BB, 4), 256, 0, stream>>>(yt2, W2, b2, Det2, yq, stats2);
    k_coefG<84, 64, 8><<<dim3(2, 64, 8), 256, 0, stream>>>(yq, D_coef_last, stats2, g2, be2, yt3);
    k_norms<<<dim3(BB, 4), 256, 0, stream>>>(yt3, ht0);
    k_fc<256, 512><<<512, 512, 0, stream>>>(ht0, Wfc1, bfc1, gfc1, befc1, ht1);
    k_fc<512, 256><<<256, 512, 0, stream>>>(ht1, Wfc2, bfc2, gfc2, befc2, ht2);
    k_out<<<BB, 256, 0, stream>>>(ht2, Wout, bout, out);
}

// Round 10
// 335.278 us; speedup vs baseline: 1.6150x; 1.1786x over previous
//
#include <hip/hip_runtime.h>
#include <hip/hip_bf16.h>

#define BB 64
#define NN 2048
#define QQ 1024
#define SS 512
#define NCH 8
#define PREPB 609
#define QKN3 4

__device__ const int PIDX[36] = {
    0, 2, 5, 8, 12, 17, 22, 27, 32, 38, 45, 52, 59, 66, 73, 80,
    88, 97, 106, 115, 124, 133, 142, 151, 160,
    170, 181, 192, 203, 214, 225, 236, 247, 258, 269, 280};

// ---------------- merged prep + shells ----------------
__global__ __launch_bounds__(256) void k_preshell(
    const float* __restrict__ De0, const float* __restrict__ De1, const float* __restrict__ De2,
    float* __restrict__ Dg0t, float* __restrict__ rs0,
    float* __restrict__ Det1, float* __restrict__ Det2,
    float* __restrict__ stats,
    const float* __restrict__ x, const float* __restrict__ dirs, float* __restrict__ pbuf) {
    __shared__ float tile[32][33];
    __shared__ float4 lx[NN / NCH];
    int blk = blockIdx.x, tid = threadIdx.x;
    if (blk < PREPB) {
        int r = tid >> 5, c = tid & 31;
        if (blk < 192) {  // D_eval1 -> Det1 [165][1024]
            int tq = blk & 31, tt = blk >> 5;
            int q0 = tq * 32, t0 = tt * 32;
            for (int rr = r; rr < 32; rr += 8) {
                int t = t0 + c;
                tile[rr][c] = (t < 165) ? De1[(q0 + rr) * 165 + t] : 0.f;
            }
            __syncthreads();
            for (int rr = r; rr < 32; rr += 8) {
                int t = t0 + rr;
                if (t < 165) Det1[t * QQ + q0 + c] = tile[c][rr];
            }
        } else if (blk < 288) {  // D_eval2 -> Det2 [84][1024]
            int i = blk - 192;
            int tq = i & 31, tt = i >> 5;
            int q0 = tq * 32, t0 = tt * 32;
            for (int rr = r; rr < 32; rr += 8) {
                int t = t0 + c;
                tile[rr][c] = (t < 84) ? De2[(q0 + rr) * 84 + t] : 0.f;
            }
            __syncthreads();
            for (int rr = r; rr < 32; rr += 8) {
                int t = t0 + rr;
                if (t < 84) Det2[t * QQ + q0 + c] = tile[c][rr];
            }
        } else if (blk < 352) {  // gather D_eval0[:, PIDX] -> Dg0t [36][1024]
            int i = blk - 288;
            int tq = i & 31, tj = i >> 5;
            int q0 = tq * 32, j0 = tj * 32;
            for (int rr = r; rr < 32; rr += 8) {
                int j = j0 + c;
                tile[rr][c] = (j < 36) ? De0[(q0 + rr) * 286 + PIDX[j]] : 0.f;
            }
            __syncthreads();
            for (int rr = r; rr < 32; rr += 8) {
                int j = j0 + rr;
                if (j < 36) Dg0t[j * QQ + q0 + c] = tile[c][rr];
            }
        } else if (blk < 608) {  // rowsum: one q per wave
            int w = tid >> 6, lane = tid & 63;
            int q = (blk - 352) * 4 + w;
            float s = 0.f;
#pragma unroll
            for (int p = 0; p < 5; p++) {
                int idx = lane + p * 64;
                if (idx < 286) s += De0[q * 286 + idx];
            }
#pragma unroll
            for (int o = 32; o > 0; o >>= 1) s += __shfl_xor(s, o, 64);
            if (lane == 0) rs0[q] = s;
        } else {
            if (tid < 224) stats[tid] = 0.f;
        }
        return;
    }
    // ---- shells path ----
    int s = blk - PREPB;
    int b = s & 63, rest = s >> 6;
    int shell = rest % 3, zc = rest / 3;
    const float KL = 18.033688011112042f;  // log2(e)/SIGMA2, SIGMA2=0.08
    const float* xb = x + ((size_t)b * NN + zc * (NN / NCH)) * 3;
    for (int n = tid; n < NN / NCH; n += 256) {
        float X = xb[n * 3 + 0];
        float Y = xb[n * 3 + 1];
        float Z = xb[n * 3 + 2];
        lx[n] = make_float4(X, Y, Z, -KL * (X * X + Y * Y + Z * Z));
    }
    __syncthreads();
    float r = (shell == 0) ? 0.4f : ((shell == 1) ? 0.8f : 1.2f);
    int s0 = tid, s1 = tid + 256;
    float cx0 = r * dirs[(shell * SS + s0) * 3 + 0];
    float cy0 = r * dirs[(shell * SS + s0) * 3 + 1];
    float cz0 = r * dirs[(shell * SS + s0) * 3 + 2];
    float cx1 = r * dirs[(shell * SS + s1) * 3 + 0];
    float cy1 = r * dirs[(shell * SS + s1) * 3 + 1];
    float cz1 = r * dirs[(shell * SS + s1) * 3 + 2];
    float base0 = -KL * (cx0 * cx0 + cy0 * cy0 + cz0 * cz0);
    float base1 = -KL * (cx1 * cx1 + cy1 * cy1 + cz1 * cz1);
    float cxs0 = 2.f * KL * cx0, cys0 = 2.f * KL * cy0, czs0 = 2.f * KL * cz0;
    float cxs1 = 2.f * KL * cx1, cys1 = 2.f * KL * cy1, czs1 = 2.f * KL * cz1;
    float a0 = 0.f, a1 = 0.f;
#pragma unroll 8
    for (int n = 0; n < NN / NCH; n++) {
        float4 p = lx[n];
        a0 += __builtin_amdgcn_exp2f(fmaf(cxs0, p.x, fmaf(cys0, p.y, fmaf(czs0, p.z, p.w + base0))));
        a1 += __builtin_amdgcn_exp2f(fmaf(cxs1, p.x, fmaf(cys1, p.y, fmaf(czs1, p.z, p.w + base1))));
    }
    float* o = pbuf + ((size_t)(zc * 3 + shell) * BB + b) * SS;
    o[s0] = a0;
    o[s1] = a1;
}

// ---------------- sh: per-b chunk reduce + SH projection + W0 mix ----------------
__global__ __launch_bounds__(1024) void k_sh(const float* __restrict__ pbuf,
                                             const float* __restrict__ A_sh,
                                             const float* __restrict__ W0,
                                             float* __restrict__ lm_ws) {
    __shared__ float lf[3][SS];
    __shared__ float lsh[36][3];
    int b = blockIdx.x, tid = threadIdx.x;
    for (int i = tid; i < 3 * SS; i += 1024) {
        int c = i / SS, s = i % SS;
        float v = 0.f;
#pragma unroll
        for (int zc = 0; zc < NCH; zc++) v += pbuf[((size_t)(zc * 3 + c) * BB + b) * SS + s];
        lf[c][s] = v * (1.0f / NN);
    }
    __syncthreads();
    int w = tid >> 6, lane = tid & 63;
    for (int p = w; p < 108; p += 16) {
        int j = p / 3, c = p % 3;
        const float* As = A_sh + j * SS;
        float a = 0.f;
#pragma unroll
        for (int k = 0; k < 8; k++) a = fmaf(lf[c][lane + 64 * k], As[lane + 64 * k], a);
#pragma unroll
        for (int o = 32; o > 0; o >>= 1) a += __shfl_xor(a, o, 64);
        if (lane == 0) lsh[j][c] = a;
    }
    __syncthreads();
    for (int i = tid; i < 576; i += 1024) {
        int j = i >> 4, u = i & 15;
        float m = 0.f;
#pragma unroll
        for (int c = 0; c < 3; c++) m = fmaf(lsh[j][c], W0[c * 16 + u], m);
        lm_ws[b * 576 + i] = m;
    }
}

// ---------------- eval0q: sparse Wigner eval + bias*rowsum + fused stats ----------------
__global__ __launch_bounds__(256) void k_eval0q(const float* __restrict__ lm_ws,
                                                const float* __restrict__ b0,
                                                const float* __restrict__ Dg0t,
                                                const float* __restrict__ rs0,
                                                float* __restrict__ yq, float* __restrict__ stats) {
    __shared__ float llm[576];
    __shared__ float lred[4][32];
    int qc = blockIdx.x, b = blockIdx.y, tid = threadIdx.x;
    for (int i = tid; i < 576; i += 256) llm[i] = lm_ws[b * 576 + i];
    __syncthreads();
    int q = qc * 256 + tid;
    float acc[16];
#pragma unroll
    for (int u = 0; u < 16; u++) acc[u] = 0.f;
#pragma unroll 4
    for (int j = 0; j < 36; j++) {
        float d = Dg0t[j * QQ + q];
#pragma unroll
        for (int u = 0; u < 16; u++) acc[u] = fmaf(d, llm[j * 16 + u], acc[u]);
    }
    float rb = rs0[q];
#pragma unroll
    for (int u = 0; u < 16; u++) acc[u] = fmaf(b0[u], rb, acc[u]);
#pragma unroll
    for (int u = 0; u < 16; u++) yq[((size_t)b * 16 + u) * QQ + q] = acc[u];
    int lane = tid & 63, w = tid >> 6;
#pragma unroll
    for (int u = 0; u < 16; u++) {
        float v = acc[u], v2 = acc[u] * acc[u];
#pragma unroll
        for (int o = 32; o > 0; o >>= 1) {
            v += __shfl_xor(v, o, 64);
            v2 += __shfl_xor(v2, o, 64);
        }
        if (lane == 0) { lred[w][u] = v; lred[w][16 + u] = v2; }
    }
    __syncthreads();
    if (tid < 32) atomicAdd(&stats[tid], lred[0][tid] + lred[1][tid] + lred[2][tid] + lred[3][tid]);
}

// ---------------- coef GEMM: float4 staging, float4 partial stores ----------------
template <int TT, int UU, int QKN>
__global__ __launch_bounds__(256) void k_coefG(const float* __restrict__ yq,
                                               const float* __restrict__ Dc,
                                               const float* __restrict__ stats,
                                               const float* __restrict__ g,
                                               const float* __restrict__ be,
                                               float* __restrict__ part) {
    constexpr int KC = QQ / QKN;
    __shared__ float lA[32][68];
    __shared__ float lB[32][68];
    __shared__ float lsu[UU], ltu[UU];
    int mt = blockIdx.x, nt = blockIdx.y, qk = blockIdx.z, tid = threadIdx.x;
    int m0 = mt * 64, n0 = nt * 64, k0 = qk * KC;
    if (tid < UU) {
        const float inv = 1.0f / (BB * QQ);
        float mm = stats[tid] * inv;
        float var = stats[UU + tid] * inv - mm * mm;
        float s = g[tid] * rsqrtf(fmaxf(var, 0.f) + 1e-3f);
        lsu[tid] = s;
        ltu[tid] = be[tid] - mm * s;
    }
    __syncthreads();
    int r = tid >> 2;
    int f = (tid & 3) * 4;
    bool mok = (m0 + r) < TT;
    const float* arow = Dc + (size_t)(mok ? (m0 + r) : 0) * QQ;
    const float* brow = yq + (size_t)(n0 + r) * QQ;
    float su = lsu[(n0 + r) % UU], tu = ltu[(n0 + r) % UU];
    int tg = tid >> 4, ug = tid & 15;
    float acc[4][4];
#pragma unroll
    for (int i = 0; i < 4; i++)
#pragma unroll
        for (int j = 0; j < 4; j++) acc[i][j] = 0.f;
    for (int kb = 0; kb < KC; kb += 32) {
        int kg = k0 + kb;
#pragma unroll
        for (int p = 0; p < 2; p++) {
            int ko = f + p * 16;
            float4 a4 = make_float4(0.f, 0.f, 0.f, 0.f);
            if (mok) a4 = *(const float4*)(arow + kg + ko);
            float4 b4 = *(const float4*)(brow + kg + ko);
#pragma unroll
            for (int i = 0; i < 4; i++) {
                float v = fmaf((&b4.x)[i], su, tu);
                lA[ko + i][r] = (&a4.x)[i];
                lB[ko + i][r] = (v > 0.f) ? v : 0.3f * v;
            }
        }
        __syncthreads();
#pragma unroll 2
        for (int kk = 0; kk < 32; kk++) {
            float4 a4 = *(const float4*)&lA[kk][tg * 4];
            float4 b4 = *(const float4*)&lB[kk][ug * 4];
#pragma unroll
            for (int i = 0; i < 4; i++) {
                float av = (&a4.x)[i];
                acc[i][0] = fmaf(av, b4.x, acc[i][0]);
                acc[i][1] = fmaf(av, b4.y, acc[i][1]);
                acc[i][2] = fmaf(av, b4.z, acc[i][2]);
                acc[i][3] = fmaf(av, b4.w, acc[i][3]);
            }
        }
        __syncthreads();
    }
    int n = n0 + ug * 4;
    int b = n / UU, u0 = n % UU;
#pragma unroll
    for (int i = 0; i < 4; i++) {
        int t = m0 + tg * 4 + i;
        if (t < TT)
            *(float4*)&part[(((size_t)qk * BB + b) * TT + t) * UU + u0] =
                make_float4(acc[i][0], acc[i][1], acc[i][2], acc[i][3]);
    }
}

// ---------------- reduce QKN=8 partials -> yt ----------------
template <int N>
__global__ __launch_bounds__(256) void k_red(const float* __restrict__ part, float* __restrict__ yt) {
    int i = (blockIdx.x * 256 + threadIdx.x) * 4;
    if (i >= N) return;
    float4 s = make_float4(0.f, 0.f, 0.f, 0.f);
#pragma unroll
    for (int k = 0; k < 8; k++) {
        float4 v = *(const float4*)&part[(size_t)k * N + i];
        s.x += v.x; s.y += v.y; s.z += v.z; s.w += v.w;
    }
    *(float4*)&yt[i] = s;
}

// ---------------- generic eval: mix(W,b) + Wigner eval + fused stats ----------------
template <int TT, int CC, int UU>
__global__ __launch_bounds__(256) void k_eval(const float* __restrict__ yt,
                                              const float* __restrict__ W, const float* __restrict__ bias,
                                              const float* __restrict__ Det,
                                              float* __restrict__ yq, float* __restrict__ stats) {
    __shared__ float lyt[TT * CC];
    __shared__ float lym[TT * 16];
    __shared__ float lred[4][32];
    int qc = blockIdx.x, b = blockIdx.y, uz = blockIdx.z * 16, tid = threadIdx.x;
    for (int i = tid; i < TT * CC; i += 256) lyt[i] = yt[(size_t)b * TT * CC + i];
    __syncthreads();
    for (int e = tid; e < TT * 16; e += 256) {
        int t = e >> 4, ul = e & 15, u = uz + ul;
        float m = bias[u];
#pragma unroll
        for (int c = 0; c < CC; c++) m = fmaf(lyt[t * CC + c], W[c * UU + u], m);
        lym[e] = m;
    }
    __syncthreads();
    int q = qc * 256 + tid;
    float acc[16];
#pragma unroll
    for (int u = 0; u < 16; u++) acc[u] = 0.f;
#pragma unroll 4
    for (int t = 0; t < TT; t++) {
        float d = Det[t * QQ + q];
#pragma unroll
        for (int u = 0; u < 16; u++) acc[u] = fmaf(d, lym[t * 16 + u], acc[u]);
    }
#pragma unroll
    for (int u = 0; u < 16; u++) yq[((size_t)b * UU + uz + u) * QQ + q] = acc[u];
    int lane = tid & 63, w = tid >> 6;
#pragma unroll
    for (int u = 0; u < 16; u++) {
        float v = acc[u], v2 = acc[u] * acc[u];
#pragma unroll
        for (int o = 32; o > 0; o >>= 1) {
            v += __shfl_xor(v, o, 64);
            v2 += __shfl_xor(v2, o, 64);
        }
        if (lane == 0) { lred[w][u] = v; lred[w][16 + u] = v2; }
    }
    __syncthreads();
    if (tid < 32) {
        float s = lred[0][tid] + lred[1][tid] + lred[2][tid] + lred[3][tid];
        int idx = (tid < 16) ? (uz + tid) : (UU + uz + tid - 16);
        atomicAdd(&stats[idx], s);
    }
}

// ---------------- norms: reduce coef3 partials in LDS, then degree-wise norms ----------------
__global__ __launch_bounds__(256) void k_norms(const float* __restrict__ part, float* __restrict__ ht0) {
    __shared__ float ly[84 * 64];
    int b = blockIdx.x, tid = threadIdx.x;
    for (int i = tid; i < 84 * 64; i += 256) {
        float v = 0.f;
#pragma unroll
        for (int k = 0; k < QKN3; k++) v += part[(size_t)k * (BB * 84 * 64) + b * (84 * 64) + i];
        ly[i] = v;
    }
    __syncthreads();
    int blk = tid >> 6, u = tid & 63;
    const int offs[4] = {0, 1, 10, 35};
    const int ends[4] = {1, 10, 35, 84};
    float a = 0.f;
    for (int t = offs[blk]; t < ends[blk]; t++) {
        float v = ly[t * 64 + u];
        a = fmaf(v, v, a);
    }
    ht0[(blk * 64 + u) * BB + b] = sqrtf(fmaxf(a, 0.f));
}

// ---------------- fc + batch-BN + relu: 8-way k-split, 4-acc unroll ----------------
template <int K, int J>
__global__ __launch_bounds__(512) void k_fc(const float* __restrict__ in, const float* __restrict__ W,
                                            const float* __restrict__ bias, const float* __restrict__ g,
                                            const float* __restrict__ be, float* __restrict__ out) {
    __shared__ float red[8][64];
    int j = blockIdx.x;
    int b = threadIdx.x & 63, kq = threadIdx.x >> 6;
    constexpr int KS = K / 8;
    int kbeg = kq * KS;
    float a0 = 0.f, a1 = 0.f, a2 = 0.f, a3 = 0.f;
#pragma unroll 4
    for (int k = kbeg; k < kbeg + KS; k += 4) {
        a0 = fmaf(in[k * BB + b], W[(size_t)k * J + j], a0);
        a1 = fmaf(in[(k + 1) * BB + b], W[(size_t)(k + 1) * J + j], a1);
        a2 = fmaf(in[(k + 2) * BB + b], W[(size_t)(k + 2) * J + j], a2);
        a3 = fmaf(in[(k + 3) * BB + b], W[(size_t)(k + 3) * J + j], a3);
    }
    red[kq][b] = (a0 + a1) + (a2 + a3);
    __syncthreads();
    if (kq == 0) {
        float acc = bias[j];
#pragma unroll
        for (int i = 0; i < 8; i++) acc += red[i][b];
        float s1 = acc, s2 = acc * acc;
#pragma unroll
        for (int o = 32; o > 0; o >>= 1) {
            s1 += __shfl_xor(s1, o, 64);
            s2 += __shfl_xor(s2, o, 64);
        }
        float m = s1 * (1.0f / 64.f);
        float var = s2 * (1.0f / 64.f) - m * m;
        float sc = g[j] * rsqrtf(fmaxf(var, 0.f) + 1e-3f);
        float v = (acc - m) * sc + be[j];
        out[j * BB + b] = fmaxf(v, 0.f);
    }
}

// ---------------- output layer + softmax: 4-way k-split, 4-acc unroll ----------------
__global__ __launch_bounds__(256) void k_out(const float* __restrict__ ht2, const float* __restrict__ Wout,
                                             const float* __restrict__ bout, float* __restrict__ outp) {
    __shared__ float red[4][64];
    __shared__ float sm[64];
    int b = blockIdx.x;
    int o = threadIdx.x & 63, kq = threadIdx.x >> 6;
    float a0 = 0.f, a1 = 0.f, a2 = 0.f, a3 = 0.f;
    int kbeg = kq * 64;
    if (o < 40) {
#pragma unroll 4
        for (int k = kbeg; k < kbeg + 64; k += 4) {
            a0 = fmaf(ht2[k * BB + b], Wout[k * 40 + o], a0);
            a1 = fmaf(ht2[(k + 1) * BB + b], Wout[(k + 1) * 40 + o], a1);
            a2 = fmaf(ht2[(k + 2) * BB + b], Wout[(k + 2) * 40 + o], a2);
            a3 = fmaf(ht2[(k + 3) * BB + b], Wout[(k + 3) * 40 + o], a3);
        }
    }
    red[kq][o] = (a0 + a1) + (a2 + a3);
    __syncthreads();
    if (kq == 0) {
        float acc = red[0][o] + red[1][o] + red[2][o] + red[3][o] + ((o < 40) ? bout[o] : 0.f);
        sm[o] = (o < 40) ? acc : -3.0e38f;
        __syncthreads();
        for (int s = 32; s > 0; s >>= 1) {
            if (o < s) sm[o] = fmaxf(sm[o], sm[o + s]);
            __syncthreads();
        }
        float m = sm[0];
        __syncthreads();
        const float L2E = 1.4426950408889634f;
        float e = (o < 40) ? exp2f((acc - m) * L2E) : 0.f;
        sm[o] = e;
        __syncthreads();
        for (int s = 32; s > 0; s >>= 1) {
            if (o < s) sm[o] += sm[o + s];
            __syncthreads();
        }
        if (o < 40) outp[b * 40 + o] = e / sm[0];
    }
}

// ---------------- workspace layout (float offsets) ----------------
#define OFF_PBUF 0          // 786432
#define OFF_DG0T 786432     // 36864
#define OFF_RS0 823296      // 1024
#define OFF_DET1 824320     // 168960
#define OFF_DET2 993280     // 86016
#define OFF_LM 1079296      // 36864
#define OFF_YQ 1116160      // 4194304
#define OFF_PART 5310464    // max(8*168960, 8*172032, 4*344064) = 1376256
#define OFF_YT 6686720      // yt1 168960 + yt2 172032 = 340992
#define OFF_HT0 7027712     // 16384
#define OFF_HT1 7044096     // 32768
#define OFF_HT2 7076864     // 16384
#define OFF_STATS 7093248   // 224

extern "C" void kernel_launch(void* const* d_in, const int* in_sizes, int n_in,
                              void* d_out, int out_size, void* d_ws, size_t ws_size,
                              hipStream_t stream) {
    const float* x = (const float*)d_in[0];
    const float* shell_dirs = (const float*)d_in[1];
    const float* A_sh = (const float*)d_in[2];
    const float* D_eval0 = (const float*)d_in[3];
    const float* D_eval1 = (const float*)d_in[4];
    const float* D_eval2 = (const float*)d_in[5];
    const float* D_coef1 = (const float*)d_in[6];
    const float* D_coef2 = (const float*)d_in[7];
    const float* D_coef_last = (const float*)d_in[8];
    const float* W0 = (const float*)d_in[9];
    const float* b0 = (const float*)d_in[10];
    const float* W1 = (const float*)d_in[11];
    const float* b1 = (const float*)d_in[12];
    const float* W2 = (const float*)d_in[13];
    const float* b2 = (const float*)d_in[14];
    const float* g0 = (const float*)d_in[15];
    const float* be0 = (const float*)d_in[16];
    const float* g1 = (const float*)d_in[17];
    const float* be1 = (const float*)d_in[18];
    const float* g2 = (const float*)d_in[19];
    const float* be2 = (const float*)d_in[20];
    const float* Wfc1 = (const float*)d_in[21];
    const float* bfc1 = (const float*)d_in[22];
    const float* gfc1 = (const float*)d_in[23];
    const float* befc1 = (const float*)d_in[24];
    const float* Wfc2 = (const float*)d_in[25];
    const float* bfc2 = (const float*)d_in[26];
    const float* gfc2 = (const float*)d_in[27];
    const float* befc2 = (const float*)d_in[28];
    const float* Wout = (const float*)d_in[29];
    const float* bout = (const float*)d_in[30];
    float* out = (float*)d_out;

    float* ws = (float*)d_ws;
    float* pbuf = ws + OFF_PBUF;
    float* Dg0t = ws + OFF_DG0T;
    float* rs0 = ws + OFF_RS0;
    float* Det1 = ws + OFF_DET1;
    float* Det2 = ws + OFF_DET2;
    float* lm_ws = ws + OFF_LM;
    float* yq = ws + OFF_YQ;
    float* part = ws + OFF_PART;
    float* yt1 = ws + OFF_YT;       // 168960
    float* yt2 = yt1 + 168960;      // 172032
    float* ht0 = ws + OFF_HT0;
    float* ht1 = ws + OFF_HT1;
    float* ht2 = ws + OFF_HT2;
    float* stats = ws + OFF_STATS;
    float* stats0 = stats;
    float* stats1 = stats + 32;
    float* stats2 = stats + 96;

    k_preshell<<<PREPB + BB * 3 * NCH, 256, 0, stream>>>(
        D_eval0, D_eval1, D_eval2, Dg0t, rs0, Det1, Det2, stats, x, shell_dirs, pbuf);
    k_sh<<<BB, 1024, 0, stream>>>(pbuf, A_sh, W0, lm_ws);
    k_eval0q<<<dim3(4, BB), 256, 0, stream>>>(lm_ws, b0, Dg0t, rs0, yq, stats0);
    k_coefG<165, 16, 8><<<dim3(3, 16, 8), 256, 0, stream>>>(yq, D_coef1, stats0, g0, be0, part);
    k_red<168960><<<165, 256, 0, stream>>>(part, yt1);
    k_eval<165, 16, 32><<<dim3(4, BB, 2), 256, 0, stream>>>(yt1, W1, b1, Det1, yq, stats1);
    k_coefG<84, 32, 8><<<dim3(2, 32, 8), 256, 0, stream>>>(yq, D_coef2, stats1, g1, be1, part);
    k_red<172032><<<168, 256, 0, stream>>>(part, yt2);
    k_eval<84, 32, 64><<<dim3(4, BB, 4), 256, 0, stream>>>(yt2, W2, b2, Det2, yq, stats2);
    k_coefG<84, 64, QKN3><<<dim3(2, 64, QKN3), 256, 0, stream>>>(yq, D_coef_last, stats2, g2, be2, part);
    k_norms<<<BB, 256, 0, stream>>>(part, ht0);
    k_fc<256, 512><<<512, 512, 0, stream>>>(ht0, Wfc1, bfc1, gfc1, befc1, ht1);
    k_fc<512, 256><<<256, 512, 0, stream>>>(ht1, Wfc2, bfc2, gfc2, befc2, ht2);
    k_out<<<BB, 256, 0, stream>>>(ht2, Wout, bout, out);
}